// Round 1
// baseline (12257.557 us; speedup 1.0000x reference)
//
#include <hip/hip_runtime.h>
#include <hip/hip_bf16.h>

#define THREADS 256

// ---------------- degree ----------------
__global__ __launch_bounds__(256) void k_deg_count(const int* __restrict__ dst, int E, int* __restrict__ degi) {
    int e = blockIdx.x * THREADS + threadIdx.x;
    if (e < E) atomicAdd(&degi[dst[e]], 1);
}

__global__ __launch_bounds__(256) void k_deg_inv(const int* __restrict__ degi, float* __restrict__ dinv, int N) {
    int i = blockIdx.x * THREADS + threadIdx.x;
    if (i < N) dinv[i] = 1.0f / (float)max(degi[i], 1);
}

// ---------------- layer-1 scatter: agg1[dst] += x[src]  (256 floats/edge) ----------------
__global__ __launch_bounds__(256) void k_scatter1(const int* __restrict__ src, const int* __restrict__ dst,
                                                  const float* __restrict__ x, float* __restrict__ agg, int E) {
    int gid = blockIdx.x * THREADS + threadIdx.x;
    int e = gid >> 6, lane = gid & 63;
    if (e >= E) return;
    int s = src[e], d = dst[e];
    const float4 v = *reinterpret_cast<const float4*>(x + ((size_t)s << 8) + (lane << 2));
    float* p = agg + ((size_t)d << 8) + (lane << 2);
    atomicAdd(p + 0, v.x);
    atomicAdd(p + 1, v.y);
    atomicAdd(p + 2, v.z);
    atomicAdd(p + 3, v.w);
}

// ---------------- GEMM1: h = relu((agg*dinv) @ W1l + x @ W1r + b1), M x 256 x 256 ----------------
__global__ __launch_bounds__(256) void k_gemm1(
    const float* __restrict__ agg, const float* __restrict__ dinv,
    const float* __restrict__ x,
    const float* __restrict__ W1l, const float* __restrict__ W1r,
    const float* __restrict__ b1, float* __restrict__ h, int M)
{
    __shared__ float As1[16][64];
    __shared__ float As2[16][64];
    __shared__ float Bs1[16][64];
    __shared__ float Bs2[16][64];

    const int tid = threadIdx.x;
    const int row0 = blockIdx.x * 64;
    const int col0 = blockIdx.y * 64;

    const int la_row = tid >> 2;          // 0..63
    const int la_k   = (tid & 3) << 2;    // 0,4,8,12
    const int lb_k   = tid >> 4;          // 0..15
    const int lb_j   = (tid & 15) << 2;   // 0..60
    const int ty = tid >> 4, tx = tid & 15;

    const int arow = row0 + la_row;
    const bool aok = arow < M;
    const float ds = aok ? dinv[arow] : 0.0f;
    const float4 z4 = make_float4(0.f, 0.f, 0.f, 0.f);

    float acc[4][4] = {};

    for (int k0 = 0; k0 < 256; k0 += 16) {
        float4 a1 = aok ? *reinterpret_cast<const float4*>(agg + (size_t)arow * 256 + k0 + la_k) : z4;
        float4 a2 = aok ? *reinterpret_cast<const float4*>(x   + (size_t)arow * 256 + k0 + la_k) : z4;
        float4 bv1 = *reinterpret_cast<const float4*>(W1l + (size_t)(k0 + lb_k) * 256 + col0 + lb_j);
        float4 bv2 = *reinterpret_cast<const float4*>(W1r + (size_t)(k0 + lb_k) * 256 + col0 + lb_j);
        __syncthreads();
        As1[la_k + 0][la_row] = a1.x * ds;
        As1[la_k + 1][la_row] = a1.y * ds;
        As1[la_k + 2][la_row] = a1.z * ds;
        As1[la_k + 3][la_row] = a1.w * ds;
        As2[la_k + 0][la_row] = a2.x;
        As2[la_k + 1][la_row] = a2.y;
        As2[la_k + 2][la_row] = a2.z;
        As2[la_k + 3][la_row] = a2.w;
        *reinterpret_cast<float4*>(&Bs1[lb_k][lb_j]) = bv1;
        *reinterpret_cast<float4*>(&Bs2[lb_k][lb_j]) = bv2;
        __syncthreads();
        #pragma unroll
        for (int k = 0; k < 16; k++) {
            float a1v[4], a2v[4], b1v[4], b2v[4];
            *reinterpret_cast<float4*>(a1v) = *reinterpret_cast<const float4*>(&As1[k][ty << 2]);
            *reinterpret_cast<float4*>(a2v) = *reinterpret_cast<const float4*>(&As2[k][ty << 2]);
            *reinterpret_cast<float4*>(b1v) = *reinterpret_cast<const float4*>(&Bs1[k][tx << 2]);
            *reinterpret_cast<float4*>(b2v) = *reinterpret_cast<const float4*>(&Bs2[k][tx << 2]);
            #pragma unroll
            for (int i = 0; i < 4; i++)
                #pragma unroll
                for (int j = 0; j < 4; j++)
                    acc[i][j] += a1v[i] * b1v[j] + a2v[i] * b2v[j];
        }
    }

    const float4 bias = *reinterpret_cast<const float4*>(b1 + col0 + (tx << 2));
    #pragma unroll
    for (int i = 0; i < 4; i++) {
        int r = row0 + (ty << 2) + i;
        if (r < M) {
            float4 o;
            o.x = fmaxf(acc[i][0] + bias.x, 0.f);
            o.y = fmaxf(acc[i][1] + bias.y, 0.f);
            o.z = fmaxf(acc[i][2] + bias.z, 0.f);
            o.w = fmaxf(acc[i][3] + bias.w, 0.f);
            *reinterpret_cast<float4*>(h + (size_t)r * 256 + col0 + (tx << 2)) = o;
        }
    }
}

// ---------------- GEMM2: TU = h @ [W2l | W2r]  -> [M, 80]  (t = cols 0..39, u = cols 40..79) ----------------
__global__ __launch_bounds__(256) void k_gemm2(
    const float* __restrict__ h, const float* __restrict__ W2l, const float* __restrict__ W2r,
    float* __restrict__ TU, int M)
{
    __shared__ float As[16][64];
    __shared__ float Bs[16][80];
    const int tid = threadIdx.x;
    const int row0 = blockIdx.x * 64;
    const int la_row = tid >> 2, la_k = (tid & 3) << 2;
    const int ty = tid >> 4, tx = tid & 15;
    const int arow = row0 + la_row;
    const bool aok = arow < M;

    float acc[4][5] = {};

    for (int k0 = 0; k0 < 256; k0 += 16) {
        float4 a = aok ? *reinterpret_cast<const float4*>(h + (size_t)arow * 256 + k0 + la_k)
                       : make_float4(0.f, 0.f, 0.f, 0.f);
        float bvals[5];
        #pragma unroll
        for (int i = 0; i < 5; i++) {
            int idx = i * 256 + tid;     // 0..1279
            int kk = idx / 80, jj = idx % 80;
            bvals[i] = (jj < 40) ? W2l[(size_t)(k0 + kk) * 40 + jj]
                                 : W2r[(size_t)(k0 + kk) * 40 + (jj - 40)];
        }
        __syncthreads();
        As[la_k + 0][la_row] = a.x;
        As[la_k + 1][la_row] = a.y;
        As[la_k + 2][la_row] = a.z;
        As[la_k + 3][la_row] = a.w;
        #pragma unroll
        for (int i = 0; i < 5; i++) {
            int idx = i * 256 + tid;
            (&Bs[0][0])[idx] = bvals[i];
        }
        __syncthreads();
        #pragma unroll
        for (int k = 0; k < 16; k++) {
            float av[4];
            *reinterpret_cast<float4*>(av) = *reinterpret_cast<const float4*>(&As[k][ty << 2]);
            float bv[5];
            #pragma unroll
            for (int j = 0; j < 5; j++) bv[j] = Bs[k][tx * 5 + j];
            #pragma unroll
            for (int i = 0; i < 4; i++)
                #pragma unroll
                for (int j = 0; j < 5; j++)
                    acc[i][j] += av[i] * bv[j];
        }
        __syncthreads();
    }

    #pragma unroll
    for (int i = 0; i < 4; i++) {
        int r = row0 + (ty << 2) + i;
        if (r < M) {
            #pragma unroll
            for (int j = 0; j < 5; j++)
                TU[(size_t)r * 80 + tx * 5 + j] = acc[i][j];
        }
    }
}

// ---------------- layer-2 scatter: aggt[dst] += t[src]  (40 floats/edge) ----------------
__global__ __launch_bounds__(256) void k_scatter2(const int* __restrict__ src, const int* __restrict__ dst,
                                                  const float* __restrict__ TU, float* __restrict__ aggt, int E) {
    int gid = blockIdx.x * THREADS + threadIdx.x;
    int e = gid >> 6, lane = gid & 63;
    if (e >= E || lane >= 40) return;
    int s = src[e], d = dst[e];
    atomicAdd(&aggt[(size_t)d * 40 + lane], TU[(size_t)s * 80 + lane]);
}

// ---------------- final: out = log_softmax(aggt*dinv + u + b2), wave per row ----------------
__global__ __launch_bounds__(256) void k_final(const float* __restrict__ aggt, const float* __restrict__ dinv,
                                               const float* __restrict__ TU, const float* __restrict__ b2,
                                               float* __restrict__ out, int M) {
    int gid = blockIdx.x * THREADS + threadIdx.x;
    int row = gid >> 6, lane = gid & 63;
    if (row >= M) return;
    float v = -1e30f;
    if (lane < 40)
        v = aggt[(size_t)row * 40 + lane] * dinv[row] + TU[(size_t)row * 80 + 40 + lane] + b2[lane];
    float m = v;
    #pragma unroll
    for (int o = 32; o > 0; o >>= 1) m = fmaxf(m, __shfl_xor(m, o, 64));
    float e = (lane < 40) ? expf(v - m) : 0.f;
    float s = e;
    #pragma unroll
    for (int o = 32; o > 0; o >>= 1) s += __shfl_xor(s, o, 64);
    if (lane < 40) out[(size_t)row * 40 + lane] = v - m - logf(s);
}

extern "C" void kernel_launch(void* const* d_in, const int* in_sizes, int n_in,
                              void* d_out, int out_size, void* d_ws, size_t ws_size,
                              hipStream_t stream) {
    const float* x   = (const float*)d_in[0];
    const int*   ei  = (const int*)d_in[1];
    const float* W1l = (const float*)d_in[2];
    const float* W1r = (const float*)d_in[3];
    const float* b1  = (const float*)d_in[4];
    const float* W2l = (const float*)d_in[5];
    const float* W2r = (const float*)d_in[6];
    const float* b2  = (const float*)d_in[7];
    float* out = (float*)d_out;

    const int N = in_sizes[0] / 256;
    const int E = in_sizes[1] / 2;
    const int* src = ei;
    const int* dst = ei + E;

    char* ws = (char*)d_ws;
    int*   degi = (int*)(ws);
    float* dinv = (float*)(ws + (size_t)N * 4);
    float* agg1 = (float*)(ws + (size_t)N * 8);
    float* hbuf = (float*)(ws + (size_t)N * 8 + (size_t)N * 256 * 4);
    // after gemm1, agg1's region is dead -> reuse it for TU and aggt
    float* TU   = agg1;                                        // N*80 floats
    float* aggt = (float*)((char*)agg1 + (size_t)N * 80 * 4);  // N*40 floats

    // zero accumulators (every call: harness does not re-poison between replays)
    hipMemsetAsync(degi, 0, (size_t)N * 4, stream);
    hipMemsetAsync(agg1, 0, (size_t)N * 256 * 4, stream);

    k_deg_count<<<(E + THREADS - 1) / THREADS, THREADS, 0, stream>>>(dst, E, degi);
    k_deg_inv<<<(N + THREADS - 1) / THREADS, THREADS, 0, stream>>>(degi, dinv, N);

    // layer 1 aggregation: wave per edge, 819M f32 atomics
    k_scatter1<<<(E * 64 + THREADS - 1) / THREADS, THREADS, 0, stream>>>(src, dst, x, agg1, E);

    dim3 g1((N + 63) / 64, 4);
    k_gemm1<<<g1, THREADS, 0, stream>>>(agg1, dinv, x, W1l, W1r, b1, hbuf, N);

    // zero aggt AFTER gemm1 (region overlaps agg1)
    hipMemsetAsync(aggt, 0, (size_t)N * 40 * 4, stream);

    k_gemm2<<<(N + 63) / 64, THREADS, 0, stream>>>(hbuf, W2l, W2r, TU, N);

    k_scatter2<<<(E * 64 + THREADS - 1) / THREADS, THREADS, 0, stream>>>(src, dst, TU, aggt, E);

    k_final<<<((size_t)N * 64 + THREADS - 1) / THREADS, THREADS, 0, stream>>>(aggt, dinv, TU, b2, out, N);
}

// Round 2
// 1916.636 us; speedup vs baseline: 6.3954x; 6.3954x over previous
//
#include <hip/hip_runtime.h>
#include <hip/hip_bf16.h>

#define THREADS 256

// ---------------- degree histogram ----------------
__global__ __launch_bounds__(256) void k_deg_count(const int* __restrict__ dst, int E, int* __restrict__ degi) {
    int e = blockIdx.x * THREADS + threadIdx.x;
    if (e < E) atomicAdd(&degi[dst[e]], 1);
}

// ---------------- single-block exclusive scan: rowptr = exscan(degi), rowptr[N] = E ----------------
__global__ __launch_bounds__(1024) void k_scan(const int* __restrict__ degi, int* __restrict__ rowptr, int N) {
    __shared__ int sm[1024];
    __shared__ int s_running;
    const int tid = threadIdx.x;
    if (tid == 0) s_running = 0;
    __syncthreads();
    for (int base = 0; base < N; base += 1024) {
        int i = base + tid;
        int v = (i < N) ? degi[i] : 0;
        sm[tid] = v;
        __syncthreads();
        #pragma unroll
        for (int off = 1; off < 1024; off <<= 1) {
            int t = (tid >= off) ? sm[tid - off] : 0;
            __syncthreads();
            sm[tid] += t;
            __syncthreads();
        }
        int incl = sm[tid];
        int run = s_running;
        if (i < N) rowptr[i] = run + incl - v;
        __syncthreads();
        if (tid == 1023) s_running = run + incl;
        __syncthreads();
    }
    if (tid == 0) rowptr[N] = s_running;
}

// ---------------- dinv + cursor init ----------------
__global__ __launch_bounds__(256) void k_prep(const int* __restrict__ degi, const int* __restrict__ rowptr,
                                              float* __restrict__ dinv, int* __restrict__ cursor, int N) {
    int i = blockIdx.x * THREADS + threadIdx.x;
    if (i < N) {
        dinv[i] = 1.0f / (float)max(degi[i], 1);
        cursor[i] = rowptr[i];
    }
}

// ---------------- CSR fill: csr_src grouped by dst ----------------
__global__ __launch_bounds__(256) void k_csr_fill(const int* __restrict__ src, const int* __restrict__ dst,
                                                  int* __restrict__ cursor, int* __restrict__ csr_src, int E) {
    int e = blockIdx.x * THREADS + threadIdx.x;
    if (e < E) {
        int p = atomicAdd(&cursor[dst[e]], 1);
        csr_src[p] = src[e];
    }
}

// ---------------- layer-1 gather-aggregate: wave per node, agg[i] = dinv[i] * sum_{s in N(i)} x[s] ----------------
__global__ __launch_bounds__(256) void k_agg1(const int* __restrict__ rowptr, const int* __restrict__ csr_src,
                                              const float* __restrict__ dinv, const float* __restrict__ x,
                                              float* __restrict__ agg, int N) {
    int gid = blockIdx.x * THREADS + threadIdx.x;
    int node = gid >> 6, lane = gid & 63;
    if (node >= N) return;
    const int e0 = rowptr[node], e1 = rowptr[node + 1];
    float4 acc = make_float4(0.f, 0.f, 0.f, 0.f);
    for (int eb = e0; eb < e1; eb += 64) {
        int n = min(64, e1 - eb);
        int sidx = (eb + lane < e1) ? csr_src[eb + lane] : 0;
        for (int j = 0; j < n; j++) {
            int s = __shfl(sidx, j, 64);
            const float4 v = *reinterpret_cast<const float4*>(x + ((size_t)s << 8) + (lane << 2));
            acc.x += v.x; acc.y += v.y; acc.z += v.z; acc.w += v.w;
        }
    }
    const float ds = dinv[node];
    acc.x *= ds; acc.y *= ds; acc.z *= ds; acc.w *= ds;
    *reinterpret_cast<float4*>(agg + ((size_t)node << 8) + (lane << 2)) = acc;
}

// ---------------- GEMM1: h = relu(agg @ W1l + x @ W1r + b1), M x 256 x 256 ----------------
__global__ __launch_bounds__(256) void k_gemm1(
    const float* __restrict__ agg, const float* __restrict__ x,
    const float* __restrict__ W1l, const float* __restrict__ W1r,
    const float* __restrict__ b1, float* __restrict__ h, int M)
{
    __shared__ float As1[16][64];
    __shared__ float As2[16][64];
    __shared__ float Bs1[16][64];
    __shared__ float Bs2[16][64];

    const int tid = threadIdx.x;
    const int row0 = blockIdx.x * 64;
    const int col0 = blockIdx.y * 64;

    const int la_row = tid >> 2;          // 0..63
    const int la_k   = (tid & 3) << 2;    // 0,4,8,12
    const int lb_k   = tid >> 4;          // 0..15
    const int lb_j   = (tid & 15) << 2;   // 0..60
    const int ty = tid >> 4, tx = tid & 15;

    const int arow = row0 + la_row;
    const bool aok = arow < M;
    const float4 z4 = make_float4(0.f, 0.f, 0.f, 0.f);

    float acc[4][4] = {};

    for (int k0 = 0; k0 < 256; k0 += 16) {
        float4 a1 = aok ? *reinterpret_cast<const float4*>(agg + (size_t)arow * 256 + k0 + la_k) : z4;
        float4 a2 = aok ? *reinterpret_cast<const float4*>(x   + (size_t)arow * 256 + k0 + la_k) : z4;
        float4 bv1 = *reinterpret_cast<const float4*>(W1l + (size_t)(k0 + lb_k) * 256 + col0 + lb_j);
        float4 bv2 = *reinterpret_cast<const float4*>(W1r + (size_t)(k0 + lb_k) * 256 + col0 + lb_j);
        __syncthreads();
        As1[la_k + 0][la_row] = a1.x;
        As1[la_k + 1][la_row] = a1.y;
        As1[la_k + 2][la_row] = a1.z;
        As1[la_k + 3][la_row] = a1.w;
        As2[la_k + 0][la_row] = a2.x;
        As2[la_k + 1][la_row] = a2.y;
        As2[la_k + 2][la_row] = a2.z;
        As2[la_k + 3][la_row] = a2.w;
        *reinterpret_cast<float4*>(&Bs1[lb_k][lb_j]) = bv1;
        *reinterpret_cast<float4*>(&Bs2[lb_k][lb_j]) = bv2;
        __syncthreads();
        #pragma unroll
        for (int k = 0; k < 16; k++) {
            float a1v[4], a2v[4], b1v[4], b2v[4];
            *reinterpret_cast<float4*>(a1v) = *reinterpret_cast<const float4*>(&As1[k][ty << 2]);
            *reinterpret_cast<float4*>(a2v) = *reinterpret_cast<const float4*>(&As2[k][ty << 2]);
            *reinterpret_cast<float4*>(b1v) = *reinterpret_cast<const float4*>(&Bs1[k][tx << 2]);
            *reinterpret_cast<float4*>(b2v) = *reinterpret_cast<const float4*>(&Bs2[k][tx << 2]);
            #pragma unroll
            for (int i = 0; i < 4; i++)
                #pragma unroll
                for (int j = 0; j < 4; j++)
                    acc[i][j] += a1v[i] * b1v[j] + a2v[i] * b2v[j];
        }
    }

    const float4 bias = *reinterpret_cast<const float4*>(b1 + col0 + (tx << 2));
    #pragma unroll
    for (int i = 0; i < 4; i++) {
        int r = row0 + (ty << 2) + i;
        if (r < M) {
            float4 o;
            o.x = fmaxf(acc[i][0] + bias.x, 0.f);
            o.y = fmaxf(acc[i][1] + bias.y, 0.f);
            o.z = fmaxf(acc[i][2] + bias.z, 0.f);
            o.w = fmaxf(acc[i][3] + bias.w, 0.f);
            *reinterpret_cast<float4*>(h + (size_t)r * 256 + col0 + (tx << 2)) = o;
        }
    }
}

// ---------------- GEMM2: TU = h @ [W2l | W2r]  -> [M, 80] ----------------
__global__ __launch_bounds__(256) void k_gemm2(
    const float* __restrict__ h, const float* __restrict__ W2l, const float* __restrict__ W2r,
    float* __restrict__ TU, int M)
{
    __shared__ float As[16][64];
    __shared__ float Bs[16][80];
    const int tid = threadIdx.x;
    const int row0 = blockIdx.x * 64;
    const int la_row = tid >> 2, la_k = (tid & 3) << 2;
    const int ty = tid >> 4, tx = tid & 15;
    const int arow = row0 + la_row;
    const bool aok = arow < M;

    float acc[4][5] = {};

    for (int k0 = 0; k0 < 256; k0 += 16) {
        float4 a = aok ? *reinterpret_cast<const float4*>(h + (size_t)arow * 256 + k0 + la_k)
                       : make_float4(0.f, 0.f, 0.f, 0.f);
        float bvals[5];
        #pragma unroll
        for (int i = 0; i < 5; i++) {
            int idx = i * 256 + tid;     // 0..1279
            int kk = idx / 80, jj = idx % 80;
            bvals[i] = (jj < 40) ? W2l[(size_t)(k0 + kk) * 40 + jj]
                                 : W2r[(size_t)(k0 + kk) * 40 + (jj - 40)];
        }
        __syncthreads();
        As[la_k + 0][la_row] = a.x;
        As[la_k + 1][la_row] = a.y;
        As[la_k + 2][la_row] = a.z;
        As[la_k + 3][la_row] = a.w;
        #pragma unroll
        for (int i = 0; i < 5; i++) {
            int idx = i * 256 + tid;
            (&Bs[0][0])[idx] = bvals[i];
        }
        __syncthreads();
        #pragma unroll
        for (int k = 0; k < 16; k++) {
            float av[4];
            *reinterpret_cast<float4*>(av) = *reinterpret_cast<const float4*>(&As[k][ty << 2]);
            float bv[5];
            #pragma unroll
            for (int j = 0; j < 5; j++) bv[j] = Bs[k][tx * 5 + j];
            #pragma unroll
            for (int i = 0; i < 4; i++)
                #pragma unroll
                for (int j = 0; j < 5; j++)
                    acc[i][j] += av[i] * bv[j];
        }
        __syncthreads();
    }

    #pragma unroll
    for (int i = 0; i < 4; i++) {
        int r = row0 + (ty << 2) + i;
        if (r < M) {
            #pragma unroll
            for (int j = 0; j < 5; j++)
                TU[(size_t)r * 80 + tx * 5 + j] = acc[i][j];
        }
    }
}

// ---------------- fused layer-2 gather + log_softmax: wave per node ----------------
__global__ __launch_bounds__(256) void k_final(const int* __restrict__ rowptr, const int* __restrict__ csr_src,
                                               const float* __restrict__ dinv, const float* __restrict__ TU,
                                               const float* __restrict__ b2, float* __restrict__ out, int N) {
    int gid = blockIdx.x * THREADS + threadIdx.x;
    int node = gid >> 6, lane = gid & 63;
    if (node >= N) return;
    const int e0 = rowptr[node], e1 = rowptr[node + 1];
    float acc = 0.f;
    for (int eb = e0; eb < e1; eb += 64) {
        int n = min(64, e1 - eb);
        int sidx = (eb + lane < e1) ? csr_src[eb + lane] : 0;
        for (int j = 0; j < n; j++) {
            int s = __shfl(sidx, j, 64);
            if (lane < 40) acc += TU[(size_t)s * 80 + lane];
        }
    }
    float v = -1e30f;
    if (lane < 40)
        v = acc * dinv[node] + TU[(size_t)node * 80 + 40 + lane] + b2[lane];
    float m = v;
    #pragma unroll
    for (int o = 32; o > 0; o >>= 1) m = fmaxf(m, __shfl_xor(m, o, 64));
    float e = (lane < 40) ? expf(v - m) : 0.f;
    float s = e;
    #pragma unroll
    for (int o = 32; o > 0; o >>= 1) s += __shfl_xor(s, o, 64);
    if (lane < 40) out[(size_t)node * 40 + lane] = v - m - logf(s);
}

extern "C" void kernel_launch(void* const* d_in, const int* in_sizes, int n_in,
                              void* d_out, int out_size, void* d_ws, size_t ws_size,
                              hipStream_t stream) {
    const float* x   = (const float*)d_in[0];
    const int*   ei  = (const int*)d_in[1];
    const float* W1l = (const float*)d_in[2];
    const float* W1r = (const float*)d_in[3];
    const float* b1  = (const float*)d_in[4];
    const float* W2l = (const float*)d_in[5];
    const float* W2r = (const float*)d_in[6];
    const float* b2  = (const float*)d_in[7];
    float* out = (float*)d_out;

    const int N = in_sizes[0] / 256;
    const int E = in_sizes[1] / 2;
    const int* src = ei;
    const int* dst = ei + E;

    char* ws = (char*)d_ws;
    size_t off = 0;
    int*   degi    = (int*)(ws + off); off += (size_t)N * 4;
    int*   rowptr  = (int*)(ws + off); off += (size_t)(N + 1) * 4;
    float* dinv    = (float*)(ws + off); off += (size_t)N * 4;
    int*   cursor  = (int*)(ws + off); off += (size_t)N * 4;
    int*   csr_src = (int*)(ws + off); off += (size_t)E * 4;
    off = (off + 255) & ~(size_t)255;
    float* agg1    = (float*)(ws + off); off += (size_t)N * 256 * 4;
    float* hbuf    = (float*)(ws + off); off += (size_t)N * 256 * 4;
    float* TU      = agg1;   // agg1 dead after gemm1; reuse for [N,80]

    hipMemsetAsync(degi, 0, (size_t)N * 4, stream);

    k_deg_count<<<(E + THREADS - 1) / THREADS, THREADS, 0, stream>>>(dst, E, degi);
    k_scan<<<1, 1024, 0, stream>>>(degi, rowptr, N);
    k_prep<<<(N + THREADS - 1) / THREADS, THREADS, 0, stream>>>(degi, rowptr, dinv, cursor, N);
    k_csr_fill<<<(E + THREADS - 1) / THREADS, THREADS, 0, stream>>>(src, dst, cursor, csr_src, E);

    k_agg1<<<((size_t)N * 64 + THREADS - 1) / THREADS, THREADS, 0, stream>>>(rowptr, csr_src, dinv, x, agg1, N);

    dim3 g1((N + 63) / 64, 4);
    k_gemm1<<<g1, THREADS, 0, stream>>>(agg1, x, W1l, W1r, b1, hbuf, N);

    k_gemm2<<<(N + 63) / 64, THREADS, 0, stream>>>(hbuf, W2l, W2r, TU, N);

    k_final<<<((size_t)N * 64 + THREADS - 1) / THREADS, THREADS, 0, stream>>>(rowptr, csr_src, dinv, TU, b2, out, N);
}

// Round 3
// 999.992 us; speedup vs baseline: 12.2577x; 1.9167x over previous
//
#include <hip/hip_runtime.h>
#include <hip/hip_bf16.h>

#define THREADS 256

typedef __attribute__((ext_vector_type(8))) short bf16x8;
typedef __attribute__((ext_vector_type(4))) float f32x4;

__device__ __forceinline__ unsigned short f2b(float f) {
    __hip_bfloat16 h = __float2bfloat16(f);
    return *reinterpret_cast<unsigned short*>(&h);
}
__device__ __forceinline__ float b2f_lo(unsigned u) {
    unsigned v = u << 16;
    return __builtin_bit_cast(float, v);
}
__device__ __forceinline__ float b2f_hi(unsigned u) {
    unsigned v = u & 0xffff0000u;
    return __builtin_bit_cast(float, v);
}
__device__ __forceinline__ float b2f(unsigned short u) {
    unsigned v = ((unsigned)u) << 16;
    return __builtin_bit_cast(float, v);
}
__device__ __forceinline__ void gload_lds16(const void* g, void* l) {
    __builtin_amdgcn_global_load_lds(
        (const __attribute__((address_space(1))) void*)g,
        (__attribute__((address_space(3))) void*)l, 16, 0, 0);
}

// ---------------- degree histogram ----------------
__global__ __launch_bounds__(256) void k_deg_count(const int* __restrict__ dst, int E, int* __restrict__ degi) {
    int e = blockIdx.x * THREADS + threadIdx.x;
    if (e < E) atomicAdd(&degi[dst[e]], 1);
}

// ---------------- hierarchical scan: phase 1 (block sums over 2048-elem chunks) ----------------
__global__ __launch_bounds__(256) void k_scan1(const int* __restrict__ degi, int* __restrict__ bsum, int N) {
    __shared__ int sm[256];
    int t = threadIdx.x, b = blockIdx.x;
    int base = b * 2048 + t * 8;
    int s = 0;
    #pragma unroll
    for (int j = 0; j < 8; ++j) { int i = base + j; if (i < N) s += degi[i]; }
    sm[t] = s; __syncthreads();
    for (int off = 1; off < 256; off <<= 1) {
        int v = (t >= off) ? sm[t - off] : 0; __syncthreads();
        sm[t] += v; __syncthreads();
    }
    if (t == 255) bsum[b] = sm[255];
}

// ---------------- phase 2: exclusive scan of block sums (nb <= 256) ----------------
__global__ __launch_bounds__(256) void k_scan2(int* __restrict__ bsum, int nb) {
    __shared__ int sm[256];
    int t = threadIdx.x;
    int v = (t < nb) ? bsum[t] : 0;
    sm[t] = v; __syncthreads();
    for (int off = 1; off < 256; off <<= 1) {
        int u = (t >= off) ? sm[t - off] : 0; __syncthreads();
        sm[t] += u; __syncthreads();
    }
    if (t < nb) bsum[t] = sm[t] - v;
}

// ---------------- phase 3: write rowptr ----------------
__global__ __launch_bounds__(256) void k_scan3(const int* __restrict__ degi, const int* __restrict__ bsum,
                                               int* __restrict__ rowptr, int N, int E) {
    __shared__ int sm[256];
    int t = threadIdx.x, b = blockIdx.x;
    int base = b * 2048 + t * 8;
    int loc[8]; int s = 0;
    #pragma unroll
    for (int j = 0; j < 8; ++j) { int i = base + j; loc[j] = s; if (i < N) s += degi[i]; }
    sm[t] = s; __syncthreads();
    for (int off = 1; off < 256; off <<= 1) {
        int v = (t >= off) ? sm[t - off] : 0; __syncthreads();
        sm[t] += v; __syncthreads();
    }
    int tex = sm[t] - s + bsum[b];
    #pragma unroll
    for (int j = 0; j < 8; ++j) { int i = base + j; if (i < N) rowptr[i] = tex + loc[j]; }
    if (b == 0 && t == 0) rowptr[N] = E;
}

// ---------------- dinv + cursor init ----------------
__global__ __launch_bounds__(256) void k_prep(const int* __restrict__ rowptr,
                                              float* __restrict__ dinv, int* __restrict__ cursor, int N) {
    int i = blockIdx.x * THREADS + threadIdx.x;
    if (i < N) {
        int d = rowptr[i + 1] - rowptr[i];
        dinv[i] = 1.0f / (float)max(d, 1);
        cursor[i] = rowptr[i];
    }
}

// ---------------- CSR fill ----------------
__global__ __launch_bounds__(256) void k_csr_fill(const int* __restrict__ src, const int* __restrict__ dst,
                                                  int* __restrict__ cursor, int* __restrict__ csr_src, int E) {
    int e = blockIdx.x * THREADS + threadIdx.x;
    if (e < E) {
        int p = atomicAdd(&cursor[dst[e]], 1);
        csr_src[p] = src[e];
    }
}

// ---------------- convert x -> bf16 (padded rows zero) ----------------
__global__ __launch_bounds__(256) void k_cvtX(const float* __restrict__ x, unsigned short* __restrict__ xb,
                                              int N, int Npad) {
    int i = blockIdx.x * THREADS + threadIdx.x;   // one 8-elem unit
    if (i >= Npad * 32) return;
    int row = i >> 5;
    unsigned short o[8];
    if (row < N) {
        float4 v0 = reinterpret_cast<const float4*>(x)[2 * (size_t)i];
        float4 v1 = reinterpret_cast<const float4*>(x)[2 * (size_t)i + 1];
        o[0] = f2b(v0.x); o[1] = f2b(v0.y); o[2] = f2b(v0.z); o[3] = f2b(v0.w);
        o[4] = f2b(v1.x); o[5] = f2b(v1.y); o[6] = f2b(v1.z); o[7] = f2b(v1.w);
    } else {
        #pragma unroll
        for (int j = 0; j < 8; ++j) o[j] = 0;
    }
    reinterpret_cast<uint4*>(xb)[i] = *reinterpret_cast<uint4*>(o);
}

// ---------------- build WbT[n][k] = (k<256 ? W1l[k][n] : W1r[k-256][n]) in bf16 ----------------
__global__ __launch_bounds__(256) void k_cvtW(const float* __restrict__ W1l, const float* __restrict__ W1r,
                                              unsigned short* __restrict__ WbT) {
    int idx = blockIdx.x * THREADS + threadIdx.x;  // 256*512
    if (idx >= 256 * 512) return;
    int n = idx >> 9, k = idx & 511;
    float v = (k < 256) ? W1l[(size_t)k * 256 + n] : W1r[(size_t)(k - 256) * 256 + n];
    WbT[idx] = f2b(v);
}

// ---------------- layer-1 gather-aggregate (bf16): half-wave per node ----------------
__global__ __launch_bounds__(256) void k_agg1(const int* __restrict__ rowptr, const int* __restrict__ csr_src,
                                              const float* __restrict__ dinv, const unsigned short* __restrict__ xb,
                                              unsigned short* __restrict__ aggb, int N, int Npad) {
    int gid = blockIdx.x * THREADS + threadIdx.x;
    int node = gid >> 5, lane = gid & 31;
    if (node >= N) {
        if (node < Npad)
            reinterpret_cast<uint4*>(aggb + (size_t)node * 256 + lane * 8)[0] = make_uint4(0, 0, 0, 0);
        return;
    }
    const int e0 = rowptr[node], e1 = rowptr[node + 1];
    float acc[8] = {};
    for (int eb = e0; eb < e1; eb += 32) {
        int n = min(32, e1 - eb);
        int sidx = (eb + lane < e1) ? csr_src[eb + lane] : 0;
        for (int j = 0; j < n; ++j) {
            int s = __shfl(sidx, j, 32);
            uint4 v = *reinterpret_cast<const uint4*>(xb + (size_t)s * 256 + lane * 8);
            acc[0] += b2f_lo(v.x); acc[1] += b2f_hi(v.x);
            acc[2] += b2f_lo(v.y); acc[3] += b2f_hi(v.y);
            acc[4] += b2f_lo(v.z); acc[5] += b2f_hi(v.z);
            acc[6] += b2f_lo(v.w); acc[7] += b2f_hi(v.w);
        }
    }
    const float ds = dinv[node];
    unsigned short o[8];
    #pragma unroll
    for (int j = 0; j < 8; ++j) o[j] = f2b(acc[j] * ds);
    *reinterpret_cast<uint4*>(aggb + (size_t)node * 256 + lane * 8) = *reinterpret_cast<uint4*>(o);
}

// ---------------- GEMM1 (bf16 MFMA): h = relu([agg|x] @ [W1l;W1r] + b1) ----------------
// A' [Mpad][512] = aggb (k 0..255) | xb (k 256..511); B' via WbT[n=256][k=512]. Tile 128x128, BK=64.
__global__ __launch_bounds__(256) void k_gemm1(
    const unsigned short* __restrict__ aggb, const unsigned short* __restrict__ xb,
    const unsigned short* __restrict__ WbT, const float* __restrict__ b1,
    unsigned short* __restrict__ hb, int M)
{
    __shared__ unsigned short As[128 * 64];
    __shared__ unsigned short Bs[128 * 64];

    const int tid  = threadIdx.x;
    const int lane = tid & 63;
    const int wave = tid >> 6;
    const int row0 = blockIdx.x * 128;
    const int col0 = blockIdx.y * 128;
    const int wm0  = (wave >> 1) * 64;
    const int wn0  = (wave & 1) * 64;

    const int ldr = lane >> 3;        // row within 8-row chunk
    const int ldc = (lane & 7) * 8;   // col element (8 bf16 = 16B)

    f32x4 acc[4][4];
    #pragma unroll
    for (int m = 0; m < 4; ++m)
        #pragma unroll
        for (int n = 0; n < 4; ++n)
            acc[m][n] = (f32x4){0.f, 0.f, 0.f, 0.f};

    for (int kt = 0; kt < 8; ++kt) {
        const unsigned short* Abase = (kt < 4) ? aggb : xb;
        const int kcol = (kt & 3) * 64;
        __syncthreads();
        #pragma unroll
        for (int i = 0; i < 4; ++i) {
            const int c = wave * 4 + i;                  // 8-row chunk id (0..15)
            const unsigned short* ga = Abase + (size_t)(row0 + c * 8 + ldr) * 256 + kcol + ldc;
            gload_lds16(ga, &As[c * 512]);
            const unsigned short* gb = WbT + (size_t)(col0 + c * 8 + ldr) * 512 + kt * 64 + ldc;
            gload_lds16(gb, &Bs[c * 512]);
        }
        __syncthreads();
        #pragma unroll
        for (int kk = 0; kk < 2; ++kk) {
            bf16x8 af[4], bf[4];
            #pragma unroll
            for (int m = 0; m < 4; ++m)
                af[m] = *reinterpret_cast<const bf16x8*>(
                    &As[(wm0 + m * 16 + (lane & 15)) * 64 + kk * 32 + (lane >> 4) * 8]);
            #pragma unroll
            for (int n = 0; n < 4; ++n)
                bf[n] = *reinterpret_cast<const bf16x8*>(
                    &Bs[(wn0 + n * 16 + (lane & 15)) * 64 + kk * 32 + (lane >> 4) * 8]);
            #pragma unroll
            for (int m = 0; m < 4; ++m)
                #pragma unroll
                for (int n = 0; n < 4; ++n)
                    acc[m][n] = __builtin_amdgcn_mfma_f32_16x16x32_bf16(af[m], bf[n], acc[m][n], 0, 0, 0);
        }
    }

    // epilogue: C/D map col=lane&15, row=(lane>>4)*4+reg
    const int crow = (lane >> 4) * 4;
    const int ccol = lane & 15;
    #pragma unroll
    for (int n = 0; n < 4; ++n) {
        const int col = col0 + wn0 + n * 16 + ccol;
        const float bias = b1[col];
        #pragma unroll
        for (int m = 0; m < 4; ++m) {
            const int rbase = row0 + wm0 + m * 16 + crow;
            #pragma unroll
            for (int r = 0; r < 4; ++r) {
                const int row = rbase + r;
                if (row < M) {
                    float v = fmaxf(acc[m][n][r] + bias, 0.f);
                    hb[(size_t)row * 256 + col] = f2b(v);
                }
            }
        }
    }
}

// ---------------- GEMM2 (f32 VALU, bf16 A): TU = h @ [W2l | W2r] -> [M, 80] ----------------
__global__ __launch_bounds__(256) void k_gemm2(
    const unsigned short* __restrict__ hb, const float* __restrict__ W2l, const float* __restrict__ W2r,
    float* __restrict__ TU, int M)
{
    __shared__ float As[16][64];
    __shared__ float Bs[16][80];
    const int tid = threadIdx.x;
    const int row0 = blockIdx.x * 64;
    const int la_row = tid >> 2, la_k = (tid & 3) << 2;
    const int ty = tid >> 4, tx = tid & 15;
    const int arow = row0 + la_row;
    const bool aok = arow < M;

    float acc[4][5] = {};

    for (int k0 = 0; k0 < 256; k0 += 16) {
        float a0 = 0.f, a1 = 0.f, a2 = 0.f, a3 = 0.f;
        if (aok) {
            ushort4 a = *reinterpret_cast<const ushort4*>(hb + (size_t)arow * 256 + k0 + la_k);
            a0 = b2f(a.x); a1 = b2f(a.y); a2 = b2f(a.z); a3 = b2f(a.w);
        }
        float bvals[5];
        #pragma unroll
        for (int i = 0; i < 5; ++i) {
            int idx = i * 256 + tid;
            int kk = idx / 80, jj = idx % 80;
            bvals[i] = (jj < 40) ? W2l[(size_t)(k0 + kk) * 40 + jj]
                                 : W2r[(size_t)(k0 + kk) * 40 + (jj - 40)];
        }
        __syncthreads();
        As[la_k + 0][la_row] = a0;
        As[la_k + 1][la_row] = a1;
        As[la_k + 2][la_row] = a2;
        As[la_k + 3][la_row] = a3;
        #pragma unroll
        for (int i = 0; i < 5; ++i) {
            int idx = i * 256 + tid;
            (&Bs[0][0])[idx] = bvals[i];
        }
        __syncthreads();
        #pragma unroll
        for (int k = 0; k < 16; ++k) {
            float av[4];
            *reinterpret_cast<float4*>(av) = *reinterpret_cast<const float4*>(&As[k][ty << 2]);
            float bv[5];
            #pragma unroll
            for (int j = 0; j < 5; ++j) bv[j] = Bs[k][tx * 5 + j];
            #pragma unroll
            for (int i = 0; i < 4; ++i)
                #pragma unroll
                for (int j = 0; j < 5; ++j)
                    acc[i][j] += av[i] * bv[j];
        }
        __syncthreads();
    }

    #pragma unroll
    for (int i = 0; i < 4; ++i) {
        int r = row0 + (ty << 2) + i;
        if (r < M) {
            #pragma unroll
            for (int j = 0; j < 5; ++j)
                TU[(size_t)r * 80 + tx * 5 + j] = acc[i][j];
        }
    }
}

// ---------------- fused layer-2 gather + log_softmax: wave per node ----------------
__global__ __launch_bounds__(256) void k_final(const int* __restrict__ rowptr, const int* __restrict__ csr_src,
                                               const float* __restrict__ dinv, const float* __restrict__ TU,
                                               const float* __restrict__ b2, float* __restrict__ out, int N) {
    int gid = blockIdx.x * THREADS + threadIdx.x;
    int node = gid >> 6, lane = gid & 63;
    if (node >= N) return;
    const int e0 = rowptr[node], e1 = rowptr[node + 1];
    float acc = 0.f;
    for (int eb = e0; eb < e1; eb += 64) {
        int n = min(64, e1 - eb);
        int sidx = (eb + lane < e1) ? csr_src[eb + lane] : 0;
        for (int j = 0; j < n; ++j) {
            int s = __shfl(sidx, j, 64);
            if (lane < 40) acc += TU[(size_t)s * 80 + lane];
        }
    }
    float v = -1e30f;
    if (lane < 40)
        v = acc * dinv[node] + TU[(size_t)node * 80 + 40 + lane] + b2[lane];
    float m = v;
    #pragma unroll
    for (int o = 32; o > 0; o >>= 1) m = fmaxf(m, __shfl_xor(m, o, 64));
    float e = (lane < 40) ? expf(v - m) : 0.f;
    float s = e;
    #pragma unroll
    for (int o = 32; o > 0; o >>= 1) s += __shfl_xor(s, o, 64);
    if (lane < 40) out[(size_t)node * 40 + lane] = v - m - logf(s);
}

extern "C" void kernel_launch(void* const* d_in, const int* in_sizes, int n_in,
                              void* d_out, int out_size, void* d_ws, size_t ws_size,
                              hipStream_t stream) {
    const float* x   = (const float*)d_in[0];
    const int*   ei  = (const int*)d_in[1];
    const float* W1l = (const float*)d_in[2];
    const float* W1r = (const float*)d_in[3];
    const float* b1  = (const float*)d_in[4];
    const float* W2l = (const float*)d_in[5];
    const float* W2r = (const float*)d_in[6];
    const float* b2  = (const float*)d_in[7];
    float* out = (float*)d_out;

    const int N = in_sizes[0] / 256;
    const int E = in_sizes[1] / 2;
    const int Npad = ((N + 127) / 128) * 128;
    const int* src = ei;
    const int* dst = ei + E;

    char* ws = (char*)d_ws;
    size_t off = 0;
    int*   degi    = (int*)(ws + off); off += (size_t)N * 4;
    int*   rowptr  = (int*)(ws + off); off += (size_t)(N + 1) * 4;
    float* dinv    = (float*)(ws + off); off += (size_t)N * 4;
    int*   cursor  = (int*)(ws + off); off += (size_t)N * 4;
    int*   bsum    = (int*)(ws + off); off += 256 * 4;
    int*   csr_src = (int*)(ws + off); off += (size_t)E * 4;
    off = (off + 255) & ~(size_t)255;
    unsigned short* xb   = (unsigned short*)(ws + off); off += (size_t)Npad * 256 * 2;
    unsigned short* aggb = (unsigned short*)(ws + off); off += (size_t)Npad * 256 * 2;
    unsigned short* hb   = (unsigned short*)(ws + off); off += (size_t)Npad * 256 * 2;
    unsigned short* WbT  = (unsigned short*)(ws + off); off += (size_t)256 * 512 * 2;
    float* TU            = (float*)(ws + off); off += (size_t)N * 80 * 4;

    const int nb = (N + 2047) / 2048;

    hipMemsetAsync(degi, 0, (size_t)N * 4, stream);

    k_deg_count<<<(E + THREADS - 1) / THREADS, THREADS, 0, stream>>>(dst, E, degi);
    k_scan1<<<nb, THREADS, 0, stream>>>(degi, bsum, N);
    k_scan2<<<1, THREADS, 0, stream>>>(bsum, nb);
    k_scan3<<<nb, THREADS, 0, stream>>>(degi, bsum, rowptr, N, E);
    k_prep<<<(N + THREADS - 1) / THREADS, THREADS, 0, stream>>>(rowptr, dinv, cursor, N);
    k_csr_fill<<<(E + THREADS - 1) / THREADS, THREADS, 0, stream>>>(src, dst, cursor, csr_src, E);

    k_cvtX<<<(Npad * 32 + THREADS - 1) / THREADS, THREADS, 0, stream>>>(x, xb, N, Npad);
    k_cvtW<<<(256 * 512 + THREADS - 1) / THREADS, THREADS, 0, stream>>>(W1l, W1r, WbT);

    k_agg1<<<(Npad * 32 + THREADS - 1) / THREADS, THREADS, 0, stream>>>(rowptr, csr_src, dinv, xb, aggb, N, Npad);

    dim3 g1(Npad / 128, 2);
    k_gemm1<<<g1, THREADS, 0, stream>>>(aggb, xb, WbT, b1, hb, N);

    k_gemm2<<<(N + 63) / 64, THREADS, 0, stream>>>(hb, W2l, W2r, TU, N);

    k_final<<<((size_t)N * 64 + THREADS - 1) / THREADS, THREADS, 0, stream>>>(rowptr, csr_src, dinv, TU, b2, out, N);
}

// Round 4
// 721.161 us; speedup vs baseline: 16.9970x; 1.3866x over previous
//
#include <hip/hip_runtime.h>
#include <hip/hip_bf16.h>

#define THREADS 256
#define NB_MAX 400   // buckets = ceil(N/256); N=100000 -> 391

typedef __attribute__((ext_vector_type(8))) short bf16x8;
typedef __attribute__((ext_vector_type(4))) float f32x4;

__device__ __forceinline__ unsigned short f2b(float f) {
    __hip_bfloat16 h = __float2bfloat16(f);
    return *reinterpret_cast<unsigned short*>(&h);
}
__device__ __forceinline__ float b2f_lo(unsigned u) {
    unsigned v = u << 16;
    return __builtin_bit_cast(float, v);
}
__device__ __forceinline__ float b2f_hi(unsigned u) {
    unsigned v = u & 0xffff0000u;
    return __builtin_bit_cast(float, v);
}
__device__ __forceinline__ float b2f(unsigned short u) {
    unsigned v = ((unsigned)u) << 16;
    return __builtin_bit_cast(float, v);
}
__device__ __forceinline__ void gload_lds16(const void* g, void* l) {
    __builtin_amdgcn_global_load_lds(
        (const __attribute__((address_space(1))) void*)g,
        (__attribute__((address_space(3))) void*)l, 16, 0, 0);
}

// ---------------- bucket histogram (LDS-aggregated) ----------------
__global__ __launch_bounds__(256) void k_hist(const int* __restrict__ dst, int E, int nbk,
                                              int* __restrict__ gcnt) {
    __shared__ int lc[NB_MAX];
    const int tid = threadIdx.x;
    for (int i = tid; i < nbk; i += 256) lc[i] = 0;
    __syncthreads();
    const int stride = gridDim.x * 256;
    for (int e = blockIdx.x * 256 + tid; e < E; e += stride)
        atomicAdd(&lc[dst[e] >> 8], 1);
    __syncthreads();
    for (int i = tid; i < nbk; i += 256)
        if (lc[i]) atomicAdd(&gcnt[i], lc[i]);
}

// ---------------- scan buckets: bptr = exscan(gcnt), bptr[nbk]=E; gcur=bptr ----------------
__global__ __launch_bounds__(512) void k_scanb(const int* __restrict__ gcnt, int* __restrict__ bptr,
                                               int* __restrict__ gcur, int nbk, int E) {
    __shared__ int sm[512];
    const int t = threadIdx.x;
    int v = (t < nbk) ? gcnt[t] : 0;
    sm[t] = v; __syncthreads();
    for (int off = 1; off < 512; off <<= 1) {
        int u = (t >= off) ? sm[t - off] : 0; __syncthreads();
        sm[t] += u; __syncthreads();
    }
    if (t < nbk) {
        int ex = sm[t] - v;
        bptr[t] = ex;
        gcur[t] = ex;
    }
    if (t == 0) bptr[nbk] = E;
}

// ---------------- scatter edges into bucket regions (block-aggregated reservation) ----------------
__global__ __launch_bounds__(256) void k_bucket_scatter(const int* __restrict__ src, const int* __restrict__ dst,
                                                        int* __restrict__ gcur, uint2* __restrict__ pairs,
                                                        int E, int nbk) {
    __shared__ int cnt[NB_MAX];
    __shared__ int base[NB_MAX];
    const int tid = threadIdx.x;
    const int e0 = blockIdx.x * 8192;
    for (int i = tid; i < nbk; i += 256) cnt[i] = 0;
    __syncthreads();
    #pragma unroll
    for (int j = 0; j < 32; ++j) {
        int e = e0 + j * 256 + tid;
        if (e < E) atomicAdd(&cnt[dst[e] >> 8], 1);
    }
    __syncthreads();
    for (int i = tid; i < nbk; i += 256)
        base[i] = cnt[i] ? atomicAdd(&gcur[i], cnt[i]) : 0;
    __syncthreads();
    #pragma unroll
    for (int j = 0; j < 32; ++j) {
        int e = e0 + j * 256 + tid;
        if (e < E) {
            int d = dst[e];
            int p = atomicAdd(&base[d >> 8], 1);
            pairs[p] = make_uint2((unsigned)src[e], (unsigned)d);
        }
    }
}

// ---------------- per-bucket CSR build: degrees, rowptr, dinv, csr_src ----------------
__global__ __launch_bounds__(256) void k_bucket_csr(const int* __restrict__ bptr, const uint2* __restrict__ pairs,
                                                    int* __restrict__ rowptr, float* __restrict__ dinv,
                                                    int* __restrict__ csr_src, int N, int nbk, int E) {
    __shared__ int deg[256];
    __shared__ int sm[256];
    __shared__ int cur[256];
    const int b = blockIdx.x;
    const int tid = threadIdx.x;
    const int node0 = b << 8;
    const int e0 = bptr[b], e1 = bptr[b + 1];

    deg[tid] = 0;
    __syncthreads();
    for (int e = e0 + tid; e < e1; e += 256)
        atomicAdd(&deg[pairs[e].y - node0], 1);
    __syncthreads();
    int d = deg[tid];
    sm[tid] = d; __syncthreads();
    for (int off = 1; off < 256; off <<= 1) {
        int u = (tid >= off) ? sm[tid - off] : 0; __syncthreads();
        sm[tid] += u; __syncthreads();
    }
    int ex = sm[tid] - d;
    int node = node0 + tid;
    cur[tid] = e0 + ex;
    if (node < N) {
        rowptr[node] = e0 + ex;
        dinv[node] = 1.0f / (float)max(d, 1);
    }
    if (b == nbk - 1 && tid == 0) rowptr[N] = E;
    __syncthreads();
    for (int e = e0 + tid; e < e1; e += 256) {
        uint2 u = pairs[e];
        int p = atomicAdd(&cur[u.y - node0], 1);
        csr_src[p] = (int)u.x;
    }
}

// ---------------- convert x -> bf16 (padded rows zero) ----------------
__global__ __launch_bounds__(256) void k_cvtX(const float* __restrict__ x, unsigned short* __restrict__ xb,
                                              int N, int Npad) {
    int i = blockIdx.x * THREADS + threadIdx.x;   // one 8-elem unit
    if (i >= Npad * 32) return;
    int row = i >> 5;
    unsigned short o[8];
    if (row < N) {
        float4 v0 = reinterpret_cast<const float4*>(x)[2 * (size_t)i];
        float4 v1 = reinterpret_cast<const float4*>(x)[2 * (size_t)i + 1];
        o[0] = f2b(v0.x); o[1] = f2b(v0.y); o[2] = f2b(v0.z); o[3] = f2b(v0.w);
        o[4] = f2b(v1.x); o[5] = f2b(v1.y); o[6] = f2b(v1.z); o[7] = f2b(v1.w);
    } else {
        #pragma unroll
        for (int j = 0; j < 8; ++j) o[j] = 0;
    }
    reinterpret_cast<uint4*>(xb)[i] = *reinterpret_cast<uint4*>(o);
}

// ---------------- build WbT[n][k] = (k<256 ? W1l[k][n] : W1r[k-256][n]) in bf16 ----------------
__global__ __launch_bounds__(256) void k_cvtW(const float* __restrict__ W1l, const float* __restrict__ W1r,
                                              unsigned short* __restrict__ WbT) {
    int idx = blockIdx.x * THREADS + threadIdx.x;  // 256*512
    if (idx >= 256 * 512) return;
    int n = idx >> 9, k = idx & 511;
    float v = (k < 256) ? W1l[(size_t)k * 256 + n] : W1r[(size_t)(k - 256) * 256 + n];
    WbT[idx] = f2b(v);
}

// ---------------- layer-1 gather-aggregate (bf16): half-wave per node ----------------
__global__ __launch_bounds__(256) void k_agg1(const int* __restrict__ rowptr, const int* __restrict__ csr_src,
                                              const float* __restrict__ dinv, const unsigned short* __restrict__ xb,
                                              unsigned short* __restrict__ aggb, int N, int Npad) {
    int gid = blockIdx.x * THREADS + threadIdx.x;
    int node = gid >> 5, lane = gid & 31;
    if (node >= N) {
        if (node < Npad)
            reinterpret_cast<uint4*>(aggb + (size_t)node * 256 + lane * 8)[0] = make_uint4(0, 0, 0, 0);
        return;
    }
    const int e0 = rowptr[node], e1 = rowptr[node + 1];
    float acc[8] = {};
    for (int eb = e0; eb < e1; eb += 32) {
        int n = min(32, e1 - eb);
        int sidx = (eb + lane < e1) ? csr_src[eb + lane] : 0;
        for (int j = 0; j < n; ++j) {
            int s = __shfl(sidx, j, 32);
            uint4 v = *reinterpret_cast<const uint4*>(xb + (size_t)s * 256 + lane * 8);
            acc[0] += b2f_lo(v.x); acc[1] += b2f_hi(v.x);
            acc[2] += b2f_lo(v.y); acc[3] += b2f_hi(v.y);
            acc[4] += b2f_lo(v.z); acc[5] += b2f_hi(v.z);
            acc[6] += b2f_lo(v.w); acc[7] += b2f_hi(v.w);
        }
    }
    const float ds = dinv[node];
    unsigned short o[8];
    #pragma unroll
    for (int j = 0; j < 8; ++j) o[j] = f2b(acc[j] * ds);
    *reinterpret_cast<uint4*>(aggb + (size_t)node * 256 + lane * 8) = *reinterpret_cast<uint4*>(o);
}

// ---------------- GEMM1 (bf16 MFMA): h = relu([agg|x] @ [W1l;W1r] + b1) ----------------
__global__ __launch_bounds__(256) void k_gemm1(
    const unsigned short* __restrict__ aggb, const unsigned short* __restrict__ xb,
    const unsigned short* __restrict__ WbT, const float* __restrict__ b1,
    unsigned short* __restrict__ hb, int M)
{
    __shared__ unsigned short As[128 * 64];
    __shared__ unsigned short Bs[128 * 64];

    const int tid  = threadIdx.x;
    const int lane = tid & 63;
    const int wave = tid >> 6;
    const int row0 = blockIdx.x * 128;
    const int col0 = blockIdx.y * 128;
    const int wm0  = (wave >> 1) * 64;
    const int wn0  = (wave & 1) * 64;

    const int ldr = lane >> 3;        // row within 8-row chunk
    const int ldc = (lane & 7) * 8;   // col element (8 bf16 = 16B)

    f32x4 acc[4][4];
    #pragma unroll
    for (int m = 0; m < 4; ++m)
        #pragma unroll
        for (int n = 0; n < 4; ++n)
            acc[m][n] = (f32x4){0.f, 0.f, 0.f, 0.f};

    for (int kt = 0; kt < 8; ++kt) {
        const unsigned short* Abase = (kt < 4) ? aggb : xb;
        const int kcol = (kt & 3) * 64;
        __syncthreads();
        #pragma unroll
        for (int i = 0; i < 4; ++i) {
            const int c = wave * 4 + i;                  // 8-row chunk id (0..15)
            const unsigned short* ga = Abase + (size_t)(row0 + c * 8 + ldr) * 256 + kcol + ldc;
            gload_lds16(ga, &As[c * 512]);
            const unsigned short* gb = WbT + (size_t)(col0 + c * 8 + ldr) * 512 + kt * 64 + ldc;
            gload_lds16(gb, &Bs[c * 512]);
        }
        __syncthreads();
        #pragma unroll
        for (int kk = 0; kk < 2; ++kk) {
            bf16x8 af[4], bf[4];
            #pragma unroll
            for (int m = 0; m < 4; ++m)
                af[m] = *reinterpret_cast<const bf16x8*>(
                    &As[(wm0 + m * 16 + (lane & 15)) * 64 + kk * 32 + (lane >> 4) * 8]);
            #pragma unroll
            for (int n = 0; n < 4; ++n)
                bf[n] = *reinterpret_cast<const bf16x8*>(
                    &Bs[(wn0 + n * 16 + (lane & 15)) * 64 + kk * 32 + (lane >> 4) * 8]);
            #pragma unroll
            for (int m = 0; m < 4; ++m)
                #pragma unroll
                for (int n = 0; n < 4; ++n)
                    acc[m][n] = __builtin_amdgcn_mfma_f32_16x16x32_bf16(af[m], bf[n], acc[m][n], 0, 0, 0);
        }
    }

    // epilogue: C/D map col=lane&15, row=(lane>>4)*4+reg
    const int crow = (lane >> 4) * 4;
    const int ccol = lane & 15;
    #pragma unroll
    for (int n = 0; n < 4; ++n) {
        const int col = col0 + wn0 + n * 16 + ccol;
        const float bias = b1[col];
        #pragma unroll
        for (int m = 0; m < 4; ++m) {
            const int rbase = row0 + wm0 + m * 16 + crow;
            #pragma unroll
            for (int r = 0; r < 4; ++r) {
                const int row = rbase + r;
                if (row < M) {
                    float v = fmaxf(acc[m][n][r] + bias, 0.f);
                    hb[(size_t)row * 256 + col] = f2b(v);
                }
            }
        }
    }
}

// ---------------- GEMM2 (f32 VALU, bf16 A): TU = h @ [W2l | W2r] -> [M, 80] ----------------
__global__ __launch_bounds__(256) void k_gemm2(
    const unsigned short* __restrict__ hb, const float* __restrict__ W2l, const float* __restrict__ W2r,
    float* __restrict__ TU, int M)
{
    __shared__ float As[16][64];
    __shared__ float Bs[16][80];
    const int tid = threadIdx.x;
    const int row0 = blockIdx.x * 64;
    const int la_row = tid >> 2, la_k = (tid & 3) << 2;
    const int ty = tid >> 4, tx = tid & 15;
    const int arow = row0 + la_row;
    const bool aok = arow < M;

    float acc[4][5] = {};

    for (int k0 = 0; k0 < 256; k0 += 16) {
        float a0 = 0.f, a1 = 0.f, a2 = 0.f, a3 = 0.f;
        if (aok) {
            ushort4 a = *reinterpret_cast<const ushort4*>(hb + (size_t)arow * 256 + k0 + la_k);
            a0 = b2f(a.x); a1 = b2f(a.y); a2 = b2f(a.z); a3 = b2f(a.w);
        }
        float bvals[5];
        #pragma unroll
        for (int i = 0; i < 5; ++i) {
            int idx = i * 256 + tid;
            int kk = idx / 80, jj = idx % 80;
            bvals[i] = (jj < 40) ? W2l[(size_t)(k0 + kk) * 40 + jj]
                                 : W2r[(size_t)(k0 + kk) * 40 + (jj - 40)];
        }
        __syncthreads();
        As[la_k + 0][la_row] = a0;
        As[la_k + 1][la_row] = a1;
        As[la_k + 2][la_row] = a2;
        As[la_k + 3][la_row] = a3;
        #pragma unroll
        for (int i = 0; i < 5; ++i) {
            int idx = i * 256 + tid;
            (&Bs[0][0])[idx] = bvals[i];
        }
        __syncthreads();
        #pragma unroll
        for (int k = 0; k < 16; ++k) {
            float av[4];
            *reinterpret_cast<float4*>(av) = *reinterpret_cast<const float4*>(&As[k][ty << 2]);
            float bv[5];
            #pragma unroll
            for (int j = 0; j < 5; ++j) bv[j] = Bs[k][tx * 5 + j];
            #pragma unroll
            for (int i = 0; i < 4; ++i)
                #pragma unroll
                for (int j = 0; j < 5; ++j)
                    acc[i][j] += av[i] * bv[j];
        }
        __syncthreads();
    }

    #pragma unroll
    for (int i = 0; i < 4; ++i) {
        int r = row0 + (ty << 2) + i;
        if (r < M) {
            #pragma unroll
            for (int j = 0; j < 5; ++j)
                TU[(size_t)r * 80 + tx * 5 + j] = acc[i][j];
        }
    }
}

// ---------------- fused layer-2 gather + log_softmax: wave per node ----------------
__global__ __launch_bounds__(256) void k_final(const int* __restrict__ rowptr, const int* __restrict__ csr_src,
                                               const float* __restrict__ dinv, const float* __restrict__ TU,
                                               const float* __restrict__ b2, float* __restrict__ out, int N) {
    int gid = blockIdx.x * THREADS + threadIdx.x;
    int node = gid >> 6, lane = gid & 63;
    if (node >= N) return;
    const int e0 = rowptr[node], e1 = rowptr[node + 1];
    float acc = 0.f;
    for (int eb = e0; eb < e1; eb += 64) {
        int n = min(64, e1 - eb);
        int sidx = (eb + lane < e1) ? csr_src[eb + lane] : 0;
        for (int j = 0; j < n; ++j) {
            int s = __shfl(sidx, j, 64);
            if (lane < 40) acc += TU[(size_t)s * 80 + lane];
        }
    }
    float v = -1e30f;
    if (lane < 40)
        v = acc * dinv[node] + TU[(size_t)node * 80 + 40 + lane] + b2[lane];
    float m = v;
    #pragma unroll
    for (int o = 32; o > 0; o >>= 1) m = fmaxf(m, __shfl_xor(m, o, 64));
    float e = (lane < 40) ? expf(v - m) : 0.f;
    float s = e;
    #pragma unroll
    for (int o = 32; o > 0; o >>= 1) s += __shfl_xor(s, o, 64);
    if (lane < 40) out[(size_t)node * 40 + lane] = v - m - logf(s);
}

extern "C" void kernel_launch(void* const* d_in, const int* in_sizes, int n_in,
                              void* d_out, int out_size, void* d_ws, size_t ws_size,
                              hipStream_t stream) {
    const float* x   = (const float*)d_in[0];
    const int*   ei  = (const int*)d_in[1];
    const float* W1l = (const float*)d_in[2];
    const float* W1r = (const float*)d_in[3];
    const float* b1  = (const float*)d_in[4];
    const float* W2l = (const float*)d_in[5];
    const float* W2r = (const float*)d_in[6];
    const float* b2  = (const float*)d_in[7];
    float* out = (float*)d_out;

    const int N = in_sizes[0] / 256;
    const int E = in_sizes[1] / 2;
    const int Npad = ((N + 127) / 128) * 128;
    const int nbk = (N + 255) / 256;     // buckets of 256 nodes
    const int* src = ei;
    const int* dst = ei + E;

    char* ws = (char*)d_ws;
    size_t off = 0;
    int*   gcnt    = (int*)(ws + off); off += (size_t)NB_MAX * 4;
    int*   bptr    = (int*)(ws + off); off += (size_t)(NB_MAX + 1) * 4;
    int*   gcur    = (int*)(ws + off); off += (size_t)NB_MAX * 4;
    int*   rowptr  = (int*)(ws + off); off += (size_t)(N + 1) * 4;
    float* dinv    = (float*)(ws + off); off += (size_t)N * 4;
    off = (off + 255) & ~(size_t)255;
    uint2* pairs   = (uint2*)(ws + off); off += (size_t)E * 8;
    int*   csr_src = (int*)(ws + off); off += (size_t)E * 4;
    off = (off + 255) & ~(size_t)255;
    unsigned short* xb   = (unsigned short*)(ws + off); off += (size_t)Npad * 256 * 2;
    unsigned short* aggb = (unsigned short*)(ws + off); off += (size_t)Npad * 256 * 2;
    unsigned short* hb   = (unsigned short*)(ws + off); off += (size_t)Npad * 256 * 2;
    unsigned short* WbT  = (unsigned short*)(ws + off); off += (size_t)256 * 512 * 2;
    float* TU = (float*)aggb;   // aggb dead after gemm1; gemm2 writes TU there

    hipMemsetAsync(gcnt, 0, (size_t)NB_MAX * 4, stream);

    const int nsb = (E + 8191) / 8192;
    k_hist<<<nsb, THREADS, 0, stream>>>(dst, E, nbk, gcnt);
    k_scanb<<<1, 512, 0, stream>>>(gcnt, bptr, gcur, nbk, E);
    k_bucket_scatter<<<nsb, THREADS, 0, stream>>>(src, dst, gcur, pairs, E, nbk);
    k_bucket_csr<<<nbk, THREADS, 0, stream>>>(bptr, pairs, rowptr, dinv, csr_src, N, nbk, E);

    k_cvtX<<<(Npad * 32 + THREADS - 1) / THREADS, THREADS, 0, stream>>>(x, xb, N, Npad);
    k_cvtW<<<(256 * 512 + THREADS - 1) / THREADS, THREADS, 0, stream>>>(W1l, W1r, WbT);

    k_agg1<<<(Npad * 32 + THREADS - 1) / THREADS, THREADS, 0, stream>>>(rowptr, csr_src, dinv, xb, aggb, N, Npad);

    dim3 g1(Npad / 128, 2);
    k_gemm1<<<g1, THREADS, 0, stream>>>(aggb, xb, WbT, b1, hb, N);

    k_gemm2<<<(N + 63) / 64, THREADS, 0, stream>>>(hb, W2l, W2r, TU, N);

    k_final<<<((size_t)N * 64 + THREADS - 1) / THREADS, THREADS, 0, stream>>>(rowptr, csr_src, dinv, TU, b2, out, N);
}

// Round 5
// 575.752 us; speedup vs baseline: 21.2897x; 1.2526x over previous
//
#include <hip/hip_runtime.h>
#include <hip/hip_bf16.h>

#define THREADS 256
#define NB_MAX 400   // buckets = ceil(N/256); N=100000 -> 391

typedef __attribute__((ext_vector_type(8))) short bf16x8;
typedef __attribute__((ext_vector_type(4))) float f32x4;
typedef __attribute__((ext_vector_type(2))) float f32x2;

__device__ __forceinline__ unsigned short f2b(float f) {
    __hip_bfloat16 h = __float2bfloat16(f);
    return *reinterpret_cast<unsigned short*>(&h);
}
__device__ __forceinline__ float b2f_lo(unsigned u) {
    unsigned v = u << 16;
    return __builtin_bit_cast(float, v);
}
__device__ __forceinline__ float b2f_hi(unsigned u) {
    unsigned v = u & 0xffff0000u;
    return __builtin_bit_cast(float, v);
}
__device__ __forceinline__ void gload_lds16(const void* g, void* l) {
    __builtin_amdgcn_global_load_lds(
        (const __attribute__((address_space(1))) void*)g,
        (__attribute__((address_space(3))) void*)l, 16, 0, 0);
}

// ---------------- bucket histogram (LDS-aggregated) ----------------
__global__ __launch_bounds__(256) void k_hist(const int* __restrict__ dst, int E, int nbk,
                                              int* __restrict__ gcnt) {
    __shared__ int lc[NB_MAX];
    const int tid = threadIdx.x;
    for (int i = tid; i < nbk; i += 256) lc[i] = 0;
    __syncthreads();
    const int stride = gridDim.x * 256;
    for (int e = blockIdx.x * 256 + tid; e < E; e += stride)
        atomicAdd(&lc[dst[e] >> 8], 1);
    __syncthreads();
    for (int i = tid; i < nbk; i += 256)
        if (lc[i]) atomicAdd(&gcnt[i], lc[i]);
}

// ---------------- scan buckets ----------------
__global__ __launch_bounds__(512) void k_scanb(const int* __restrict__ gcnt, int* __restrict__ bptr,
                                               int* __restrict__ gcur, int nbk, int E) {
    __shared__ int sm[512];
    const int t = threadIdx.x;
    int v = (t < nbk) ? gcnt[t] : 0;
    sm[t] = v; __syncthreads();
    for (int off = 1; off < 512; off <<= 1) {
        int u = (t >= off) ? sm[t - off] : 0; __syncthreads();
        sm[t] += u; __syncthreads();
    }
    if (t < nbk) {
        int ex = sm[t] - v;
        bptr[t] = ex;
        gcur[t] = ex;
    }
    if (t == 0) bptr[nbk] = E;
}

// ---------------- scatter edges into bucket regions ----------------
__global__ __launch_bounds__(256) void k_bucket_scatter(const int* __restrict__ src, const int* __restrict__ dst,
                                                        int* __restrict__ gcur, uint2* __restrict__ pairs,
                                                        int E, int nbk) {
    __shared__ int cnt[NB_MAX];
    __shared__ int base[NB_MAX];
    const int tid = threadIdx.x;
    const int e0 = blockIdx.x * 8192;
    for (int i = tid; i < nbk; i += 256) cnt[i] = 0;
    __syncthreads();
    #pragma unroll
    for (int j = 0; j < 32; ++j) {
        int e = e0 + j * 256 + tid;
        if (e < E) atomicAdd(&cnt[dst[e] >> 8], 1);
    }
    __syncthreads();
    for (int i = tid; i < nbk; i += 256)
        base[i] = cnt[i] ? atomicAdd(&gcur[i], cnt[i]) : 0;
    __syncthreads();
    #pragma unroll
    for (int j = 0; j < 32; ++j) {
        int e = e0 + j * 256 + tid;
        if (e < E) {
            int d = dst[e];
            int p = atomicAdd(&base[d >> 8], 1);
            pairs[p] = make_uint2((unsigned)src[e], (unsigned)d);
        }
    }
}

// ---------------- per-bucket CSR build ----------------
__global__ __launch_bounds__(256) void k_bucket_csr(const int* __restrict__ bptr, const uint2* __restrict__ pairs,
                                                    int* __restrict__ rowptr, float* __restrict__ dinv,
                                                    int* __restrict__ csr_src, int N, int nbk, int E) {
    __shared__ int deg[256];
    __shared__ int sm[256];
    __shared__ int cur[256];
    const int b = blockIdx.x;
    const int tid = threadIdx.x;
    const int node0 = b << 8;
    const int e0 = bptr[b], e1 = bptr[b + 1];

    deg[tid] = 0;
    __syncthreads();
    for (int e = e0 + tid; e < e1; e += 256)
        atomicAdd(&deg[pairs[e].y - node0], 1);
    __syncthreads();
    int d = deg[tid];
    sm[tid] = d; __syncthreads();
    for (int off = 1; off < 256; off <<= 1) {
        int u = (tid >= off) ? sm[tid - off] : 0; __syncthreads();
        sm[tid] += u; __syncthreads();
    }
    int ex = sm[tid] - d;
    int node = node0 + tid;
    cur[tid] = e0 + ex;
    if (node < N) {
        rowptr[node] = e0 + ex;
        dinv[node] = 1.0f / (float)max(d, 1);
    }
    if (b == nbk - 1 && tid == 0) rowptr[N] = E;
    __syncthreads();
    for (int e = e0 + tid; e < e1; e += 256) {
        uint2 u = pairs[e];
        int p = atomicAdd(&cur[u.y - node0], 1);
        csr_src[p] = (int)u.x;
    }
}

// ---------------- convert x -> bf16 (xb) + fp8 e4m3 (xq); padded rows zero ----------------
__global__ __launch_bounds__(256) void k_cvtX(const float* __restrict__ x, unsigned short* __restrict__ xb,
                                              unsigned char* __restrict__ xq, int N, int Npad) {
    int i = blockIdx.x * THREADS + threadIdx.x;   // one 8-elem unit
    if (i >= Npad * 32) return;
    int row = i >> 5;
    unsigned short o[8];
    int q0 = 0, q1 = 0;
    if (row < N) {
        float4 v0 = reinterpret_cast<const float4*>(x)[2 * (size_t)i];
        float4 v1 = reinterpret_cast<const float4*>(x)[2 * (size_t)i + 1];
        o[0] = f2b(v0.x); o[1] = f2b(v0.y); o[2] = f2b(v0.z); o[3] = f2b(v0.w);
        o[4] = f2b(v1.x); o[5] = f2b(v1.y); o[6] = f2b(v1.z); o[7] = f2b(v1.w);
        q0 = __builtin_amdgcn_cvt_pk_fp8_f32(v0.x, v0.y, q0, false);
        q0 = __builtin_amdgcn_cvt_pk_fp8_f32(v0.z, v0.w, q0, true);
        q1 = __builtin_amdgcn_cvt_pk_fp8_f32(v1.x, v1.y, q1, false);
        q1 = __builtin_amdgcn_cvt_pk_fp8_f32(v1.z, v1.w, q1, true);
    } else {
        #pragma unroll
        for (int j = 0; j < 8; ++j) o[j] = 0;
    }
    reinterpret_cast<uint4*>(xb)[i] = *reinterpret_cast<uint4*>(o);
    reinterpret_cast<uint2*>(xq)[i] = make_uint2((unsigned)q0, (unsigned)q1);
}

// ---------------- build WbT[n][k] for layer1 (bf16) ----------------
__global__ __launch_bounds__(256) void k_cvtW(const float* __restrict__ W1l, const float* __restrict__ W1r,
                                              unsigned short* __restrict__ WbT) {
    int idx = blockIdx.x * THREADS + threadIdx.x;  // 256*512
    if (idx >= 256 * 512) return;
    int n = idx >> 9, k = idx & 511;
    float v = (k < 256) ? W1l[(size_t)k * 256 + n] : W1r[(size_t)(k - 256) * 256 + n];
    WbT[idx] = f2b(v);
}

// ---------------- build WbT2[n=80][k=256] for layer2 (bf16) ----------------
__global__ __launch_bounds__(256) void k_cvtW2(const float* __restrict__ W2l, const float* __restrict__ W2r,
                                               unsigned short* __restrict__ WbT2) {
    int idx = blockIdx.x * THREADS + threadIdx.x;  // 80*256
    if (idx >= 80 * 256) return;
    int n = idx >> 8, k = idx & 255;
    float v = (n < 40) ? W2l[(size_t)k * 40 + n] : W2r[(size_t)k * 40 + (n - 40)];
    WbT2[idx] = f2b(v);
}

// ---------------- layer-1 gather-aggregate (fp8): half-wave per node ----------------
__global__ __launch_bounds__(256) void k_agg1(const int* __restrict__ rowptr, const int* __restrict__ csr_src,
                                              const float* __restrict__ dinv, const unsigned char* __restrict__ xq,
                                              unsigned short* __restrict__ aggb, int N, int Npad) {
    int gid = blockIdx.x * THREADS + threadIdx.x;
    int node = gid >> 5, lane = gid & 31;
    if (node >= N) {
        if (node < Npad)
            reinterpret_cast<uint4*>(aggb + (size_t)node * 256 + lane * 8)[0] = make_uint4(0, 0, 0, 0);
        return;
    }
    const int e0 = rowptr[node], e1 = rowptr[node + 1];
    float acc[8] = {};
    for (int eb = e0; eb < e1; eb += 32) {
        int n = min(32, e1 - eb);
        int sidx = (eb + lane < e1) ? csr_src[eb + lane] : 0;
        for (int j = 0; j < n; ++j) {
            int s = __shfl(sidx, j, 32);
            uint2 v = *reinterpret_cast<const uint2*>(xq + (size_t)s * 256 + lane * 8);
            f32x2 p0 = __builtin_amdgcn_cvt_pk_f32_fp8((int)v.x, false);
            f32x2 p1 = __builtin_amdgcn_cvt_pk_f32_fp8((int)v.x, true);
            f32x2 p2 = __builtin_amdgcn_cvt_pk_f32_fp8((int)v.y, false);
            f32x2 p3 = __builtin_amdgcn_cvt_pk_f32_fp8((int)v.y, true);
            acc[0] += p0.x; acc[1] += p0.y;
            acc[2] += p1.x; acc[3] += p1.y;
            acc[4] += p2.x; acc[5] += p2.y;
            acc[6] += p3.x; acc[7] += p3.y;
        }
    }
    const float ds = dinv[node];
    unsigned short o[8];
    #pragma unroll
    for (int j = 0; j < 8; ++j) o[j] = f2b(acc[j] * ds);
    *reinterpret_cast<uint4*>(aggb + (size_t)node * 256 + lane * 8) = *reinterpret_cast<uint4*>(o);
}

// ---------------- GEMM1 (bf16 MFMA, XOR-swizzled LDS): h = relu([agg|x] @ [W1l;W1r] + b1) ----------------
__global__ __launch_bounds__(256) void k_gemm1(
    const unsigned short* __restrict__ aggb, const unsigned short* __restrict__ xb,
    const unsigned short* __restrict__ WbT, const float* __restrict__ b1,
    unsigned short* __restrict__ hb, int M)
{
    __shared__ unsigned short As[128 * 64];
    __shared__ unsigned short Bs[128 * 64];

    const int tid  = threadIdx.x;
    const int lane = tid & 63;
    const int wave = tid >> 6;
    const int row0 = blockIdx.x * 128;
    const int col0 = blockIdx.y * 128;
    const int wm0  = (wave >> 1) * 64;
    const int wn0  = (wave & 1) * 64;

    const int ldr = lane >> 3;                       // row within 8-row chunk
    const int lsw = ((lane & 7) ^ ldr) * 8;          // swizzled global 8-elem slot

    f32x4 acc[4][4];
    #pragma unroll
    for (int m = 0; m < 4; ++m)
        #pragma unroll
        for (int n = 0; n < 4; ++n)
            acc[m][n] = (f32x4){0.f, 0.f, 0.f, 0.f};

    for (int kt = 0; kt < 8; ++kt) {
        const unsigned short* Abase = (kt < 4) ? aggb : xb;
        const int kcol = (kt & 3) * 64;
        __syncthreads();
        #pragma unroll
        for (int i = 0; i < 4; ++i) {
            const int c = wave * 4 + i;              // 8-row chunk id (0..15)
            const unsigned short* ga = Abase + (size_t)(row0 + c * 8 + ldr) * 256 + kcol + lsw;
            gload_lds16(ga, &As[c * 512]);
            const unsigned short* gb = WbT + (size_t)(col0 + c * 8 + ldr) * 512 + kt * 64 + lsw;
            gload_lds16(gb, &Bs[c * 512]);
        }
        __syncthreads();
        #pragma unroll
        for (int kk = 0; kk < 2; ++kk) {
            bf16x8 af[4], bf[4];
            #pragma unroll
            for (int m = 0; m < 4; ++m) {
                const int r = wm0 + m * 16 + (lane & 15);
                const int s = (kk * 4 + (lane >> 4)) ^ (r & 7);
                af[m] = *reinterpret_cast<const bf16x8*>(&As[r * 64 + s * 8]);
            }
            #pragma unroll
            for (int n = 0; n < 4; ++n) {
                const int r = wn0 + n * 16 + (lane & 15);
                const int s = (kk * 4 + (lane >> 4)) ^ (r & 7);
                bf[n] = *reinterpret_cast<const bf16x8*>(&Bs[r * 64 + s * 8]);
            }
            #pragma unroll
            for (int m = 0; m < 4; ++m)
                #pragma unroll
                for (int n = 0; n < 4; ++n)
                    acc[m][n] = __builtin_amdgcn_mfma_f32_16x16x32_bf16(af[m], bf[n], acc[m][n], 0, 0, 0);
        }
    }

    const int crow = (lane >> 4) * 4;
    const int ccol = lane & 15;
    #pragma unroll
    for (int n = 0; n < 4; ++n) {
        const int col = col0 + wn0 + n * 16 + ccol;
        const float bias = b1[col];
        #pragma unroll
        for (int m = 0; m < 4; ++m) {
            const int rbase = row0 + wm0 + m * 16 + crow;
            #pragma unroll
            for (int r = 0; r < 4; ++r) {
                const int row = rbase + r;
                if (row < M) {
                    float v = fmaxf(acc[m][n][r] + bias, 0.f);
                    hb[(size_t)row * 256 + col] = f2b(v);
                }
            }
        }
    }
}

// ---------------- GEMM2 (bf16 MFMA): [Tb|Up] = h @ [W2l|W2r]; Up includes +b2 ----------------
__global__ __launch_bounds__(256) void k_gemm2(
    const unsigned short* __restrict__ hb, const unsigned short* __restrict__ WbT2,
    const float* __restrict__ b2,
    unsigned short* __restrict__ Tb, float* __restrict__ Up, int M)
{
    __shared__ unsigned short As[128 * 64];
    __shared__ unsigned short Bs2[80 * 264];   // padded stride 264 -> conflict-free frag reads

    const int tid  = threadIdx.x;
    const int lane = tid & 63;
    const int wave = tid >> 6;
    const int row0 = blockIdx.x * 128;

    const int ldr = lane >> 3;
    const int lsw = ((lane & 7) ^ ldr) * 8;

    // load B [80][256] into padded LDS once
    for (int idx = tid; idx < 80 * 32; idx += 256) {
        int row = idx >> 5, un = idx & 31;
        uint4 d = *reinterpret_cast<const uint4*>(WbT2 + (size_t)row * 256 + un * 8);
        *reinterpret_cast<uint4*>(&Bs2[row * 264 + un * 8]) = d;
    }

    f32x4 acc[2][5];
    #pragma unroll
    for (int m = 0; m < 2; ++m)
        #pragma unroll
        for (int n = 0; n < 5; ++n)
            acc[m][n] = (f32x4){0.f, 0.f, 0.f, 0.f};

    for (int kt = 0; kt < 4; ++kt) {
        __syncthreads();
        #pragma unroll
        for (int i = 0; i < 4; ++i) {
            const int c = wave * 4 + i;
            const unsigned short* ga = hb + (size_t)(row0 + c * 8 + ldr) * 256 + kt * 64 + lsw;
            gload_lds16(ga, &As[c * 512]);
        }
        __syncthreads();
        #pragma unroll
        for (int kk = 0; kk < 2; ++kk) {
            bf16x8 af[2], bf[5];
            #pragma unroll
            for (int m = 0; m < 2; ++m) {
                const int r = wave * 32 + m * 16 + (lane & 15);
                const int s = (kk * 4 + (lane >> 4)) ^ (r & 7);
                af[m] = *reinterpret_cast<const bf16x8*>(&As[(r & 127) * 64 + s * 8]);
            }
            #pragma unroll
            for (int n = 0; n < 5; ++n) {
                const int r = n * 16 + (lane & 15);
                bf[n] = *reinterpret_cast<const bf16x8*>(&Bs2[r * 264 + kt * 64 + kk * 32 + (lane >> 4) * 8]);
            }
            #pragma unroll
            for (int m = 0; m < 2; ++m)
                #pragma unroll
                for (int n = 0; n < 5; ++n)
                    acc[m][n] = __builtin_amdgcn_mfma_f32_16x16x32_bf16(af[m], bf[n], acc[m][n], 0, 0, 0);
        }
    }

    const int crow = (lane >> 4) * 4;
    const int ccol = lane & 15;
    #pragma unroll
    for (int n = 0; n < 5; ++n) {
        const int col = n * 16 + ccol;        // 0..79
        #pragma unroll
        for (int m = 0; m < 2; ++m) {
            const int rbase = row0 + wave * 32 + m * 16 + crow;
            #pragma unroll
            for (int r = 0; r < 4; ++r) {
                const int row = rbase + r;
                if (row < M) {
                    float v = acc[m][n][r];
                    if (col < 40)
                        Tb[(size_t)row * 40 + col] = f2b(v);
                    else
                        Up[(size_t)row * 40 + (col - 40)] = v + b2[col - 40];
                }
            }
        }
    }
}

// ---------------- fused layer-2 gather (bf16 Tb) + log_softmax: wave per node ----------------
__global__ __launch_bounds__(256) void k_final(const int* __restrict__ rowptr, const int* __restrict__ csr_src,
                                               const float* __restrict__ dinv, const unsigned short* __restrict__ Tb,
                                               const float* __restrict__ Up, float* __restrict__ out, int N) {
    int gid = blockIdx.x * THREADS + threadIdx.x;
    int node = gid >> 6, lane = gid & 63;
    if (node >= N) return;
    const int e0 = rowptr[node], e1 = rowptr[node + 1];
    float a0 = 0.f, a1 = 0.f;
    for (int eb = e0; eb < e1; eb += 64) {
        int n = min(64, e1 - eb);
        int sidx = (eb + lane < e1) ? csr_src[eb + lane] : 0;
        for (int j = 0; j < n; ++j) {
            int s = __shfl(sidx, j, 64);
            if (lane < 20) {
                unsigned u = *reinterpret_cast<const unsigned*>(Tb + (size_t)s * 40 + lane * 2);
                a0 += b2f_lo(u);
                a1 += b2f_hi(u);
            }
        }
    }
    float v0 = -1e30f, v1 = -1e30f;
    if (lane < 20) {
        const float ds = dinv[node];
        float2 up = *reinterpret_cast<const float2*>(Up + (size_t)node * 40 + lane * 2);
        v0 = a0 * ds + up.x;
        v1 = a1 * ds + up.y;
    }
    float m = fmaxf(v0, v1);
    #pragma unroll
    for (int o = 32; o > 0; o >>= 1) m = fmaxf(m, __shfl_xor(m, o, 64));
    float e = (lane < 20) ? (expf(v0 - m) + expf(v1 - m)) : 0.f;
    float s = e;
    #pragma unroll
    for (int o = 32; o > 0; o >>= 1) s += __shfl_xor(s, o, 64);
    float ls = logf(s);
    if (lane < 20) {
        float2 o2;
        o2.x = v0 - m - ls;
        o2.y = v1 - m - ls;
        *reinterpret_cast<float2*>(out + (size_t)node * 40 + lane * 2) = o2;
    }
}

extern "C" void kernel_launch(void* const* d_in, const int* in_sizes, int n_in,
                              void* d_out, int out_size, void* d_ws, size_t ws_size,
                              hipStream_t stream) {
    const float* x   = (const float*)d_in[0];
    const int*   ei  = (const int*)d_in[1];
    const float* W1l = (const float*)d_in[2];
    const float* W1r = (const float*)d_in[3];
    const float* b1  = (const float*)d_in[4];
    const float* W2l = (const float*)d_in[5];
    const float* W2r = (const float*)d_in[6];
    const float* b2  = (const float*)d_in[7];
    float* out = (float*)d_out;

    const int N = in_sizes[0] / 256;
    const int E = in_sizes[1] / 2;
    const int Npad = ((N + 127) / 128) * 128;
    const int nbk = (N + 255) / 256;
    const int* src = ei;
    const int* dst = ei + E;

    char* ws = (char*)d_ws;
    size_t off = 0;
    int*   gcnt    = (int*)(ws + off); off += (size_t)NB_MAX * 4;
    int*   bptr    = (int*)(ws + off); off += (size_t)(NB_MAX + 1) * 4;
    int*   gcur    = (int*)(ws + off); off += (size_t)NB_MAX * 4;
    int*   rowptr  = (int*)(ws + off); off += (size_t)(N + 1) * 4;
    float* dinv    = (float*)(ws + off); off += (size_t)N * 4;
    off = (off + 255) & ~(size_t)255;
    uint2* pairs   = (uint2*)(ws + off); off += (size_t)E * 8;
    int*   csr_src = (int*)(ws + off); off += (size_t)E * 4;
    off = (off + 255) & ~(size_t)255;
    unsigned short* xb   = (unsigned short*)(ws + off); off += (size_t)Npad * 256 * 2;
    unsigned char*  xq   = (unsigned char*)(ws + off);  off += (size_t)Npad * 256;
    unsigned short* aggb = (unsigned short*)(ws + off); off += (size_t)Npad * 256 * 2;
    unsigned short* hb   = (unsigned short*)(ws + off); off += (size_t)Npad * 256 * 2;
    unsigned short* WbT  = (unsigned short*)(ws + off); off += (size_t)256 * 512 * 2;
    unsigned short* WbT2 = (unsigned short*)(ws + off); off += (size_t)80 * 256 * 2;
    off = (off + 255) & ~(size_t)255;
    unsigned short* Tb   = (unsigned short*)(ws + off); off += (size_t)Npad * 40 * 2;
    float*          Up   = (float*)(ws + off);          off += (size_t)Npad * 40 * 4;

    hipMemsetAsync(gcnt, 0, (size_t)NB_MAX * 4, stream);

    const int nsb = (E + 8191) / 8192;
    k_hist<<<nsb, THREADS, 0, stream>>>(dst, E, nbk, gcnt);
    k_scanb<<<1, 512, 0, stream>>>(gcnt, bptr, gcur, nbk, E);
    k_bucket_scatter<<<nsb, THREADS, 0, stream>>>(src, dst, gcur, pairs, E, nbk);
    k_bucket_csr<<<nbk, THREADS, 0, stream>>>(bptr, pairs, rowptr, dinv, csr_src, N, nbk, E);

    k_cvtX<<<(Npad * 32 + THREADS - 1) / THREADS, THREADS, 0, stream>>>(x, xb, xq, N, Npad);
    k_cvtW<<<(256 * 512 + THREADS - 1) / THREADS, THREADS, 0, stream>>>(W1l, W1r, WbT);
    k_cvtW2<<<(80 * 256 + THREADS - 1) / THREADS, THREADS, 0, stream>>>(W2l, W2r, WbT2);

    k_agg1<<<(Npad * 32 + THREADS - 1) / THREADS, THREADS, 0, stream>>>(rowptr, csr_src, dinv, xq, aggb, N, Npad);

    dim3 g1(Npad / 128, 2);
    k_gemm1<<<g1, THREADS, 0, stream>>>(aggb, xb, WbT, b1, hb, N);

    k_gemm2<<<Npad / 128, THREADS, 0, stream>>>(hb, WbT2, b2, Tb, Up, N);

    k_final<<<((size_t)N * 64 + THREADS - 1) / THREADS, THREADS, 0, stream>>>(rowptr, csr_src, dinv, Tb, Up, out, N);
}

// Round 6
// 443.795 us; speedup vs baseline: 27.6199x; 1.2973x over previous
//
#include <hip/hip_runtime.h>
#include <hip/hip_bf16.h>

#define THREADS 256
#define NB_MAX 400   // buckets = ceil(N/256); N=100000 -> 391

typedef __attribute__((ext_vector_type(8))) short bf16x8;
typedef __attribute__((ext_vector_type(4))) float f32x4;
typedef __attribute__((ext_vector_type(2))) float f32x2;

__device__ __forceinline__ unsigned short f2b(float f) {
    __hip_bfloat16 h = __float2bfloat16(f);
    return *reinterpret_cast<unsigned short*>(&h);
}
__device__ __forceinline__ float b2f_lo(unsigned u) {
    unsigned v = u << 16;
    return __builtin_bit_cast(float, v);
}
__device__ __forceinline__ float b2f_hi(unsigned u) {
    unsigned v = u & 0xffff0000u;
    return __builtin_bit_cast(float, v);
}
__device__ __forceinline__ void gload_lds16(const void* g, void* l) {
    __builtin_amdgcn_global_load_lds(
        (const __attribute__((address_space(1))) void*)g,
        (__attribute__((address_space(3))) void*)l, 16, 0, 0);
}

// ---------------- bucket histogram (LDS-aggregated) ----------------
__global__ __launch_bounds__(256) void k_hist(const int* __restrict__ dst, int E, int nbk,
                                              int* __restrict__ gcnt) {
    __shared__ int lc[NB_MAX];
    const int tid = threadIdx.x;
    for (int i = tid; i < nbk; i += 256) lc[i] = 0;
    __syncthreads();
    const int stride = gridDim.x * 256;
    for (int e = blockIdx.x * 256 + tid; e < E; e += stride)
        atomicAdd(&lc[dst[e] >> 8], 1);
    __syncthreads();
    for (int i = tid; i < nbk; i += 256)
        if (lc[i]) atomicAdd(&gcnt[i], lc[i]);
}

// ---------------- scan buckets ----------------
__global__ __launch_bounds__(512) void k_scanb(const int* __restrict__ gcnt, int* __restrict__ bptr,
                                               int* __restrict__ gcur, int nbk, int E) {
    __shared__ int sm[512];
    const int t = threadIdx.x;
    int v = (t < nbk) ? gcnt[t] : 0;
    sm[t] = v; __syncthreads();
    for (int off = 1; off < 512; off <<= 1) {
        int u = (t >= off) ? sm[t - off] : 0; __syncthreads();
        sm[t] += u; __syncthreads();
    }
    if (t < nbk) {
        int ex = sm[t] - v;
        bptr[t] = ex;
        gcur[t] = ex;
    }
    if (t == 0) bptr[nbk] = E;
}

// ---------------- scatter edges into bucket regions ----------------
__global__ __launch_bounds__(256) void k_bucket_scatter(const int* __restrict__ src, const int* __restrict__ dst,
                                                        int* __restrict__ gcur, uint2* __restrict__ pairs,
                                                        int E, int nbk) {
    __shared__ int cnt[NB_MAX];
    __shared__ int base[NB_MAX];
    const int tid = threadIdx.x;
    const int e0 = blockIdx.x * 8192;
    for (int i = tid; i < nbk; i += 256) cnt[i] = 0;
    __syncthreads();
    #pragma unroll
    for (int j = 0; j < 32; ++j) {
        int e = e0 + j * 256 + tid;
        if (e < E) atomicAdd(&cnt[dst[e] >> 8], 1);
    }
    __syncthreads();
    for (int i = tid; i < nbk; i += 256)
        base[i] = cnt[i] ? atomicAdd(&gcur[i], cnt[i]) : 0;
    __syncthreads();
    #pragma unroll
    for (int j = 0; j < 32; ++j) {
        int e = e0 + j * 256 + tid;
        if (e < E) {
            int d = dst[e];
            int p = atomicAdd(&base[d >> 8], 1);
            pairs[p] = make_uint2((unsigned)src[e], (unsigned)d);
        }
    }
}

// ---------------- per-bucket CSR build ----------------
__global__ __launch_bounds__(256) void k_bucket_csr(const int* __restrict__ bptr, const uint2* __restrict__ pairs,
                                                    int* __restrict__ rowptr, float* __restrict__ dinv,
                                                    int* __restrict__ csr_src, int N, int nbk, int E) {
    __shared__ int deg[256];
    __shared__ int sm[256];
    __shared__ int cur[256];
    const int b = blockIdx.x;
    const int tid = threadIdx.x;
    const int node0 = b << 8;
    const int e0 = bptr[b], e1 = bptr[b + 1];

    deg[tid] = 0;
    __syncthreads();
    for (int e = e0 + tid; e < e1; e += 256)
        atomicAdd(&deg[pairs[e].y - node0], 1);
    __syncthreads();
    int d = deg[tid];
    sm[tid] = d; __syncthreads();
    for (int off = 1; off < 256; off <<= 1) {
        int u = (tid >= off) ? sm[tid - off] : 0; __syncthreads();
        sm[tid] += u; __syncthreads();
    }
    int ex = sm[tid] - d;
    int node = node0 + tid;
    cur[tid] = e0 + ex;
    if (node < N) {
        rowptr[node] = e0 + ex;
        dinv[node] = 1.0f / (float)max(d, 1);
    }
    if (b == nbk - 1 && tid == 0) rowptr[N] = E;
    __syncthreads();
    for (int e = e0 + tid; e < e1; e += 256) {
        uint2 u = pairs[e];
        int p = atomicAdd(&cur[u.y - node0], 1);
        csr_src[p] = (int)u.x;
    }
}

// ---------------- convert x -> bf16 (xb) + fp8 e4m3 (xq); padded rows zero ----------------
__global__ __launch_bounds__(256) void k_cvtX(const float* __restrict__ x, unsigned short* __restrict__ xb,
                                              unsigned char* __restrict__ xq, int N, int Npad) {
    int i = blockIdx.x * THREADS + threadIdx.x;   // one 8-elem unit
    if (i >= Npad * 32) return;
    int row = i >> 5;
    unsigned short o[8];
    int q0 = 0, q1 = 0;
    if (row < N) {
        float4 v0 = reinterpret_cast<const float4*>(x)[2 * (size_t)i];
        float4 v1 = reinterpret_cast<const float4*>(x)[2 * (size_t)i + 1];
        o[0] = f2b(v0.x); o[1] = f2b(v0.y); o[2] = f2b(v0.z); o[3] = f2b(v0.w);
        o[4] = f2b(v1.x); o[5] = f2b(v1.y); o[6] = f2b(v1.z); o[7] = f2b(v1.w);
        q0 = __builtin_amdgcn_cvt_pk_fp8_f32(v0.x, v0.y, q0, false);
        q0 = __builtin_amdgcn_cvt_pk_fp8_f32(v0.z, v0.w, q0, true);
        q1 = __builtin_amdgcn_cvt_pk_fp8_f32(v1.x, v1.y, q1, false);
        q1 = __builtin_amdgcn_cvt_pk_fp8_f32(v1.z, v1.w, q1, true);
    } else {
        #pragma unroll
        for (int j = 0; j < 8; ++j) o[j] = 0;
    }
    reinterpret_cast<uint4*>(xb)[i] = *reinterpret_cast<uint4*>(o);
    reinterpret_cast<uint2*>(xq)[i] = make_uint2((unsigned)q0, (unsigned)q1);
}

// ---------------- build WbT[n][k] for layer1 (bf16) ----------------
__global__ __launch_bounds__(256) void k_cvtW(const float* __restrict__ W1l, const float* __restrict__ W1r,
                                              unsigned short* __restrict__ WbT) {
    int idx = blockIdx.x * THREADS + threadIdx.x;  // 256*512
    if (idx >= 256 * 512) return;
    int n = idx >> 9, k = idx & 511;
    float v = (k < 256) ? W1l[(size_t)k * 256 + n] : W1r[(size_t)(k - 256) * 256 + n];
    WbT[idx] = f2b(v);
}

// ---------------- build WbT2[n=80][k=256] for layer2 (bf16) ----------------
__global__ __launch_bounds__(256) void k_cvtW2(const float* __restrict__ W2l, const float* __restrict__ W2r,
                                               unsigned short* __restrict__ WbT2) {
    int idx = blockIdx.x * THREADS + threadIdx.x;  // 80*256
    if (idx >= 80 * 256) return;
    int n = idx >> 8, k = idx & 255;
    float v = (n < 40) ? W2l[(size_t)k * 40 + n] : W2r[(size_t)k * 40 + (n - 40)];
    WbT2[idx] = f2b(v);
}

// ---------------- layer-1 gather-aggregate (fp8): half-wave per node, 4 edges in flight ----------------
__global__ __launch_bounds__(256) void k_agg1(const int* __restrict__ rowptr, const int* __restrict__ csr_src,
                                              const float* __restrict__ dinv, const unsigned char* __restrict__ xq,
                                              unsigned short* __restrict__ aggb, int N, int Npad) {
    int gid = blockIdx.x * THREADS + threadIdx.x;
    int node = gid >> 5, lane = gid & 31;
    if (node >= N) {
        if (node < Npad)
            reinterpret_cast<uint4*>(aggb + (size_t)node * 256 + lane * 8)[0] = make_uint4(0, 0, 0, 0);
        return;
    }
    const int e0 = rowptr[node], e1 = rowptr[node + 1];
    const unsigned char* xl = xq + (size_t)lane * 8;
    float acc[8] = {};
    for (int eb = e0; eb < e1; eb += 32) {
        int n = min(32, e1 - eb);
        int sidx = (eb + lane < e1) ? csr_src[eb + lane] : 0;
        int j = 0;
        for (; j + 3 < n; j += 4) {
            int s0 = __shfl(sidx, j + 0, 32);
            int s1 = __shfl(sidx, j + 1, 32);
            int s2 = __shfl(sidx, j + 2, 32);
            int s3 = __shfl(sidx, j + 3, 32);
            uint2 va = *reinterpret_cast<const uint2*>(xl + (size_t)s0 * 256);
            uint2 vb = *reinterpret_cast<const uint2*>(xl + (size_t)s1 * 256);
            uint2 vc = *reinterpret_cast<const uint2*>(xl + (size_t)s2 * 256);
            uint2 vd = *reinterpret_cast<const uint2*>(xl + (size_t)s3 * 256);
            uint2 vv[4] = {va, vb, vc, vd};
            #pragma unroll
            for (int q = 0; q < 4; ++q) {
                f32x2 p0 = __builtin_amdgcn_cvt_pk_f32_fp8((int)vv[q].x, false);
                f32x2 p1 = __builtin_amdgcn_cvt_pk_f32_fp8((int)vv[q].x, true);
                f32x2 p2 = __builtin_amdgcn_cvt_pk_f32_fp8((int)vv[q].y, false);
                f32x2 p3 = __builtin_amdgcn_cvt_pk_f32_fp8((int)vv[q].y, true);
                acc[0] += p0.x; acc[1] += p0.y;
                acc[2] += p1.x; acc[3] += p1.y;
                acc[4] += p2.x; acc[5] += p2.y;
                acc[6] += p3.x; acc[7] += p3.y;
            }
        }
        for (; j < n; ++j) {
            int s = __shfl(sidx, j, 32);
            uint2 v = *reinterpret_cast<const uint2*>(xl + (size_t)s * 256);
            f32x2 p0 = __builtin_amdgcn_cvt_pk_f32_fp8((int)v.x, false);
            f32x2 p1 = __builtin_amdgcn_cvt_pk_f32_fp8((int)v.x, true);
            f32x2 p2 = __builtin_amdgcn_cvt_pk_f32_fp8((int)v.y, false);
            f32x2 p3 = __builtin_amdgcn_cvt_pk_f32_fp8((int)v.y, true);
            acc[0] += p0.x; acc[1] += p0.y;
            acc[2] += p1.x; acc[3] += p1.y;
            acc[4] += p2.x; acc[5] += p2.y;
            acc[6] += p3.x; acc[7] += p3.y;
        }
    }
    const float ds = dinv[node];
    unsigned short o[8];
    #pragma unroll
    for (int j = 0; j < 8; ++j) o[j] = f2b(acc[j] * ds);
    *reinterpret_cast<uint4*>(aggb + (size_t)node * 256 + lane * 8) = *reinterpret_cast<uint4*>(o);
}

// ---------------- GEMM1 (bf16 MFMA, XOR-swizzled LDS): h = relu([agg|x] @ [W1l;W1r] + b1) ----------------
__global__ __launch_bounds__(256) void k_gemm1(
    const unsigned short* __restrict__ aggb, const unsigned short* __restrict__ xb,
    const unsigned short* __restrict__ WbT, const float* __restrict__ b1,
    unsigned short* __restrict__ hb, int M)
{
    __shared__ unsigned short As[128 * 64];
    __shared__ unsigned short Bs[128 * 64];

    const int tid  = threadIdx.x;
    const int lane = tid & 63;
    const int wave = tid >> 6;
    const int row0 = blockIdx.x * 128;
    const int col0 = blockIdx.y * 128;
    const int wm0  = (wave >> 1) * 64;
    const int wn0  = (wave & 1) * 64;

    const int ldr = lane >> 3;                       // row within 8-row chunk
    const int lsw = ((lane & 7) ^ ldr) * 8;          // swizzled global 8-elem slot

    f32x4 acc[4][4];
    #pragma unroll
    for (int m = 0; m < 4; ++m)
        #pragma unroll
        for (int n = 0; n < 4; ++n)
            acc[m][n] = (f32x4){0.f, 0.f, 0.f, 0.f};

    for (int kt = 0; kt < 8; ++kt) {
        const unsigned short* Abase = (kt < 4) ? aggb : xb;
        const int kcol = (kt & 3) * 64;
        __syncthreads();
        #pragma unroll
        for (int i = 0; i < 4; ++i) {
            const int c = wave * 4 + i;              // 8-row chunk id (0..15)
            const unsigned short* ga = Abase + (size_t)(row0 + c * 8 + ldr) * 256 + kcol + lsw;
            gload_lds16(ga, &As[c * 512]);
            const unsigned short* gb = WbT + (size_t)(col0 + c * 8 + ldr) * 512 + kt * 64 + lsw;
            gload_lds16(gb, &Bs[c * 512]);
        }
        __syncthreads();
        #pragma unroll
        for (int kk = 0; kk < 2; ++kk) {
            bf16x8 af[4], bf[4];
            #pragma unroll
            for (int m = 0; m < 4; ++m) {
                const int r = wm0 + m * 16 + (lane & 15);
                const int s = (kk * 4 + (lane >> 4)) ^ (r & 7);
                af[m] = *reinterpret_cast<const bf16x8*>(&As[r * 64 + s * 8]);
            }
            #pragma unroll
            for (int n = 0; n < 4; ++n) {
                const int r = wn0 + n * 16 + (lane & 15);
                const int s = (kk * 4 + (lane >> 4)) ^ (r & 7);
                bf[n] = *reinterpret_cast<const bf16x8*>(&Bs[r * 64 + s * 8]);
            }
            #pragma unroll
            for (int m = 0; m < 4; ++m)
                #pragma unroll
                for (int n = 0; n < 4; ++n)
                    acc[m][n] = __builtin_amdgcn_mfma_f32_16x16x32_bf16(af[m], bf[n], acc[m][n], 0, 0, 0);
        }
    }

    const int crow = (lane >> 4) * 4;
    const int ccol = lane & 15;
    #pragma unroll
    for (int n = 0; n < 4; ++n) {
        const int col = col0 + wn0 + n * 16 + ccol;
        const float bias = b1[col];
        #pragma unroll
        for (int m = 0; m < 4; ++m) {
            const int rbase = row0 + wm0 + m * 16 + crow;
            #pragma unroll
            for (int r = 0; r < 4; ++r) {
                const int row = rbase + r;
                if (row < M) {
                    float v = fmaxf(acc[m][n][r] + bias, 0.f);
                    hb[(size_t)row * 256 + col] = f2b(v);
                }
            }
        }
    }
}

// ---------------- GEMM2 (bf16 MFMA): [Tb|Up] = h @ [W2l|W2r]; Up includes +b2 ----------------
__global__ __launch_bounds__(256) void k_gemm2(
    const unsigned short* __restrict__ hb, const unsigned short* __restrict__ WbT2,
    const float* __restrict__ b2,
    unsigned short* __restrict__ Tb, float* __restrict__ Up, int M)
{
    __shared__ unsigned short As[128 * 64];
    __shared__ unsigned short Bs2[80 * 264];   // padded stride 264 -> conflict-free frag reads

    const int tid  = threadIdx.x;
    const int lane = tid & 63;
    const int wave = tid >> 6;
    const int row0 = blockIdx.x * 128;

    const int ldr = lane >> 3;
    const int lsw = ((lane & 7) ^ ldr) * 8;

    // load B [80][256] into padded LDS once
    for (int idx = tid; idx < 80 * 32; idx += 256) {
        int row = idx >> 5, un = idx & 31;
        uint4 d = *reinterpret_cast<const uint4*>(WbT2 + (size_t)row * 256 + un * 8);
        *reinterpret_cast<uint4*>(&Bs2[row * 264 + un * 8]) = d;
    }

    f32x4 acc[2][5];
    #pragma unroll
    for (int m = 0; m < 2; ++m)
        #pragma unroll
        for (int n = 0; n < 5; ++n)
            acc[m][n] = (f32x4){0.f, 0.f, 0.f, 0.f};

    for (int kt = 0; kt < 4; ++kt) {
        __syncthreads();
        #pragma unroll
        for (int i = 0; i < 4; ++i) {
            const int c = wave * 4 + i;
            const unsigned short* ga = hb + (size_t)(row0 + c * 8 + ldr) * 256 + kt * 64 + lsw;
            gload_lds16(ga, &As[c * 512]);
        }
        __syncthreads();
        #pragma unroll
        for (int kk = 0; kk < 2; ++kk) {
            bf16x8 af[2], bf[5];
            #pragma unroll
            for (int m = 0; m < 2; ++m) {
                const int r = wave * 32 + m * 16 + (lane & 15);
                const int s = (kk * 4 + (lane >> 4)) ^ (r & 7);
                af[m] = *reinterpret_cast<const bf16x8*>(&As[(r & 127) * 64 + s * 8]);
            }
            #pragma unroll
            for (int n = 0; n < 5; ++n) {
                const int r = n * 16 + (lane & 15);
                bf[n] = *reinterpret_cast<const bf16x8*>(&Bs2[r * 264 + kt * 64 + kk * 32 + (lane >> 4) * 8]);
            }
            #pragma unroll
            for (int m = 0; m < 2; ++m)
                #pragma unroll
                for (int n = 0; n < 5; ++n)
                    acc[m][n] = __builtin_amdgcn_mfma_f32_16x16x32_bf16(af[m], bf[n], acc[m][n], 0, 0, 0);
        }
    }

    const int crow = (lane >> 4) * 4;
    const int ccol = lane & 15;
    #pragma unroll
    for (int n = 0; n < 5; ++n) {
        const int col = n * 16 + ccol;        // 0..79
        #pragma unroll
        for (int m = 0; m < 2; ++m) {
            const int rbase = row0 + wave * 32 + m * 16 + crow;
            #pragma unroll
            for (int r = 0; r < 4; ++r) {
                const int row = rbase + r;
                if (row < M) {
                    float v = acc[m][n][r];
                    if (col < 40)
                        Tb[(size_t)row * 40 + col] = f2b(v);
                    else
                        Up[(size_t)row * 40 + (col - 40)] = v + b2[col - 40];
                }
            }
        }
    }
}

// ---------------- fused layer-2 gather + log_softmax: wave per node, 6 edges per VMEM ----------------
__global__ __launch_bounds__(256) void k_final(const int* __restrict__ rowptr, const int* __restrict__ csr_src,
                                               const float* __restrict__ dinv, const unsigned short* __restrict__ Tb,
                                               const float* __restrict__ Up, float* __restrict__ out, int N) {
    int gid = blockIdx.x * THREADS + threadIdx.x;
    int node = gid >> 6, lane = gid & 63;
    if (node >= N) return;
    const int e0 = rowptr[node], e1 = rowptr[node + 1];
    const int g = lane / 10;     // edge slot 0..5 (lanes 60-63 -> g=6, inactive)
    const int c = lane % 10;     // col part: uint2 = cols c*4 .. c*4+3
    float a0 = 0.f, a1 = 0.f, a2 = 0.f, a3 = 0.f;
    for (int eb = e0; eb < e1; eb += 64) {
        int sidx = (eb + lane < e1) ? csr_src[eb + lane] : 0;
        int nn = min(64, e1 - eb);
        for (int jb = 0; jb < nn; jb += 6) {
            int ei = jb + g;
            bool valid = (g < 6) && (ei < nn);
            int s = __shfl(sidx, ei & 63, 64);
            if (valid) {
                uint2 u = *reinterpret_cast<const uint2*>(Tb + (size_t)s * 40 + c * 4);
                a0 += b2f_lo(u.x); a1 += b2f_hi(u.x);
                a2 += b2f_lo(u.y); a3 += b2f_hi(u.y);
            }
        }
    }
    // merge the 6 edge-groups: lanes (c + 10g) hold partials for col-part c.
    // shfls read pre-update values (all issued before the adds) -> no RAW hazard.
    float t0 = a0, t1 = a1, t2 = a2, t3 = a3;
    #pragma unroll
    for (int gg = 1; gg < 6; ++gg) {
        t0 += __shfl(a0, c + 10 * gg, 64);
        t1 += __shfl(a1, c + 10 * gg, 64);
        t2 += __shfl(a2, c + 10 * gg, 64);
        t3 += __shfl(a3, c + 10 * gg, 64);
    }
    float v0 = -1e30f, v1 = -1e30f, v2 = -1e30f, v3 = -1e30f;
    if (lane < 10) {
        const float ds = dinv[node];
        float4 up = *reinterpret_cast<const float4*>(Up + (size_t)node * 40 + lane * 4);
        v0 = t0 * ds + up.x; v1 = t1 * ds + up.y;
        v2 = t2 * ds + up.z; v3 = t3 * ds + up.w;
    }
    float m = fmaxf(fmaxf(v0, v1), fmaxf(v2, v3));
    #pragma unroll
    for (int o = 8; o > 0; o >>= 1) m = fmaxf(m, __shfl_xor(m, o, 16));
    float e = 0.f;
    if (lane < 10) e = expf(v0 - m) + expf(v1 - m) + expf(v2 - m) + expf(v3 - m);
    float ssum = e;
    #pragma unroll
    for (int o = 8; o > 0; o >>= 1) ssum += __shfl_xor(ssum, o, 16);
    float ls = logf(ssum);
    if (lane < 10) {
        float4 o4;
        o4.x = v0 - m - ls; o4.y = v1 - m - ls;
        o4.z = v2 - m - ls; o4.w = v3 - m - ls;
        *reinterpret_cast<float4*>(out + (size_t)node * 40 + lane * 4) = o4;
    }
}

extern "C" void kernel_launch(void* const* d_in, const int* in_sizes, int n_in,
                              void* d_out, int out_size, void* d_ws, size_t ws_size,
                              hipStream_t stream) {
    const float* x   = (const float*)d_in[0];
    const int*   ei  = (const int*)d_in[1];
    const float* W1l = (const float*)d_in[2];
    const float* W1r = (const float*)d_in[3];
    const float* b1  = (const float*)d_in[4];
    const float* W2l = (const float*)d_in[5];
    const float* W2r = (const float*)d_in[6];
    const float* b2  = (const float*)d_in[7];
    float* out = (float*)d_out;

    const int N = in_sizes[0] / 256;
    const int E = in_sizes[1] / 2;
    const int Npad = ((N + 127) / 128) * 128;
    const int nbk = (N + 255) / 256;
    const int* src = ei;
    const int* dst = ei + E;

    char* ws = (char*)d_ws;
    size_t off = 0;
    int*   gcnt    = (int*)(ws + off); off += (size_t)NB_MAX * 4;
    int*   bptr    = (int*)(ws + off); off += (size_t)(NB_MAX + 1) * 4;
    int*   gcur    = (int*)(ws + off); off += (size_t)NB_MAX * 4;
    int*   rowptr  = (int*)(ws + off); off += (size_t)(N + 1) * 4;
    float* dinv    = (float*)(ws + off); off += (size_t)N * 4;
    off = (off + 255) & ~(size_t)255;
    uint2* pairs   = (uint2*)(ws + off); off += (size_t)E * 8;
    int*   csr_src = (int*)(ws + off); off += (size_t)E * 4;
    off = (off + 255) & ~(size_t)255;
    unsigned short* xb   = (unsigned short*)(ws + off); off += (size_t)Npad * 256 * 2;
    unsigned char*  xq   = (unsigned char*)(ws + off);  off += (size_t)Npad * 256;
    unsigned short* aggb = (unsigned short*)(ws + off); off += (size_t)Npad * 256 * 2;
    unsigned short* hb   = (unsigned short*)(ws + off); off += (size_t)Npad * 256 * 2;
    unsigned short* WbT  = (unsigned short*)(ws + off); off += (size_t)256 * 512 * 2;
    unsigned short* WbT2 = (unsigned short*)(ws + off); off += (size_t)80 * 256 * 2;
    off = (off + 255) & ~(size_t)255;
    unsigned short* Tb   = (unsigned short*)(ws + off); off += (size_t)Npad * 40 * 2;
    float*          Up   = (float*)(ws + off);          off += (size_t)Npad * 40 * 4;

    hipMemsetAsync(gcnt, 0, (size_t)NB_MAX * 4, stream);

    const int nsb = (E + 8191) / 8192;
    k_hist<<<nsb, THREADS, 0, stream>>>(dst, E, nbk, gcnt);
    k_scanb<<<1, 512, 0, stream>>>(gcnt, bptr, gcur, nbk, E);
    k_bucket_scatter<<<nsb, THREADS, 0, stream>>>(src, dst, gcur, pairs, E, nbk);
    k_bucket_csr<<<nbk, THREADS, 0, stream>>>(bptr, pairs, rowptr, dinv, csr_src, N, nbk, E);

    k_cvtX<<<(Npad * 32 + THREADS - 1) / THREADS, THREADS, 0, stream>>>(x, xb, xq, N, Npad);
    k_cvtW<<<(256 * 512 + THREADS - 1) / THREADS, THREADS, 0, stream>>>(W1l, W1r, WbT);
    k_cvtW2<<<(80 * 256 + THREADS - 1) / THREADS, THREADS, 0, stream>>>(W2l, W2r, WbT2);

    k_agg1<<<(Npad * 32 + THREADS - 1) / THREADS, THREADS, 0, stream>>>(rowptr, csr_src, dinv, xq, aggb, N, Npad);

    dim3 g1(Npad / 128, 2);
    k_gemm1<<<g1, THREADS, 0, stream>>>(aggb, xb, WbT, b1, hb, N);

    k_gemm2<<<Npad / 128, THREADS, 0, stream>>>(hb, WbT2, b2, Tb, Up, N);

    k_final<<<((size_t)N * 64 + THREADS - 1) / THREADS, THREADS, 0, stream>>>(rowptr, csr_src, dinv, Tb, Up, out, N);
}

// Round 7
// 407.363 us; speedup vs baseline: 30.0900x; 1.0894x over previous
//
#include <hip/hip_runtime.h>
#include <hip/hip_bf16.h>

#define THREADS 256
#define NB_MAX 400   // buckets = ceil(N/256); N=100000 -> 391

typedef __attribute__((ext_vector_type(8))) short bf16x8;
typedef __attribute__((ext_vector_type(4))) float f32x4;
typedef __attribute__((ext_vector_type(2))) float f32x2;

__device__ __forceinline__ unsigned short f2b(float f) {
    __hip_bfloat16 h = __float2bfloat16(f);
    return *reinterpret_cast<unsigned short*>(&h);
}
__device__ __forceinline__ float b2f_lo(unsigned u) {
    unsigned v = u << 16;
    return __builtin_bit_cast(float, v);
}
__device__ __forceinline__ float b2f_hi(unsigned u) {
    unsigned v = u & 0xffff0000u;
    return __builtin_bit_cast(float, v);
}
__device__ __forceinline__ void gload_lds16(const void* g, void* l) {
    __builtin_amdgcn_global_load_lds(
        (const __attribute__((address_space(1))) void*)g,
        (__attribute__((address_space(3))) void*)l, 16, 0, 0);
}

// ---------------- bucket histogram (LDS-aggregated) ----------------
__global__ __launch_bounds__(256) void k_hist(const int* __restrict__ dst, int E, int nbk,
                                              int* __restrict__ gcnt) {
    __shared__ int lc[NB_MAX];
    const int tid = threadIdx.x;
    for (int i = tid; i < nbk; i += 256) lc[i] = 0;
    __syncthreads();
    const int stride = gridDim.x * 256;
    for (int e = blockIdx.x * 256 + tid; e < E; e += stride)
        atomicAdd(&lc[dst[e] >> 8], 1);
    __syncthreads();
    for (int i = tid; i < nbk; i += 256)
        if (lc[i]) atomicAdd(&gcnt[i], lc[i]);
}

// ---------------- scan buckets ----------------
__global__ __launch_bounds__(512) void k_scanb(const int* __restrict__ gcnt, int* __restrict__ bptr,
                                               int* __restrict__ gcur, int nbk, int E) {
    __shared__ int sm[512];
    const int t = threadIdx.x;
    int v = (t < nbk) ? gcnt[t] : 0;
    sm[t] = v; __syncthreads();
    for (int off = 1; off < 512; off <<= 1) {
        int u = (t >= off) ? sm[t - off] : 0; __syncthreads();
        sm[t] += u; __syncthreads();
    }
    if (t < nbk) {
        int ex = sm[t] - v;
        bptr[t] = ex;
        gcur[t] = ex;
    }
    if (t == 0) bptr[nbk] = E;
}

// ---------------- scatter edges into bucket regions (packed: src<<8 | dst&255) ----------------
__global__ __launch_bounds__(256) void k_bucket_scatter(const int* __restrict__ src, const int* __restrict__ dst,
                                                        int* __restrict__ gcur, unsigned* __restrict__ pairs,
                                                        int E, int nbk) {
    __shared__ int cnt[NB_MAX];
    __shared__ int base[NB_MAX];
    const int tid = threadIdx.x;
    const int e0 = blockIdx.x * 8192;
    for (int i = tid; i < nbk; i += 256) cnt[i] = 0;
    __syncthreads();
    #pragma unroll
    for (int j = 0; j < 32; ++j) {
        int e = e0 + j * 256 + tid;
        if (e < E) atomicAdd(&cnt[dst[e] >> 8], 1);
    }
    __syncthreads();
    for (int i = tid; i < nbk; i += 256)
        base[i] = cnt[i] ? atomicAdd(&gcur[i], cnt[i]) : 0;
    __syncthreads();
    #pragma unroll
    for (int j = 0; j < 32; ++j) {
        int e = e0 + j * 256 + tid;
        if (e < E) {
            int d = dst[e];
            int p = atomicAdd(&base[d >> 8], 1);
            pairs[p] = ((unsigned)src[e] << 8) | ((unsigned)d & 255u);
        }
    }
}

// ---------------- per-bucket CSR build ----------------
__global__ __launch_bounds__(256) void k_bucket_csr(const int* __restrict__ bptr, const unsigned* __restrict__ pairs,
                                                    int* __restrict__ rowptr, float* __restrict__ dinv,
                                                    int* __restrict__ csr_src, int N, int nbk, int E) {
    __shared__ int deg[256];
    __shared__ int sm[256];
    __shared__ int cur[256];
    const int b = blockIdx.x;
    const int tid = threadIdx.x;
    const int e0 = bptr[b], e1 = bptr[b + 1];

    deg[tid] = 0;
    __syncthreads();
    for (int e = e0 + tid; e < e1; e += 256)
        atomicAdd(&deg[pairs[e] & 255u], 1);
    __syncthreads();
    int d = deg[tid];
    sm[tid] = d; __syncthreads();
    for (int off = 1; off < 256; off <<= 1) {
        int u = (tid >= off) ? sm[tid - off] : 0; __syncthreads();
        sm[tid] += u; __syncthreads();
    }
    int ex = sm[tid] - d;
    int node = (b << 8) + tid;
    cur[tid] = e0 + ex;
    if (node < N) {
        rowptr[node] = e0 + ex;
        dinv[node] = 1.0f / (float)max(d, 1);
    }
    if (b == nbk - 1 && tid == 0) rowptr[N] = E;
    __syncthreads();
    for (int e = e0 + tid; e < e1; e += 256) {
        unsigned u = pairs[e];
        int p = atomicAdd(&cur[u & 255u], 1);
        csr_src[p] = (int)(u >> 8);
    }
}

// ---------------- convert x -> bf16 (xb) + fp8 e4m3 (xq); padded rows zero ----------------
__global__ __launch_bounds__(256) void k_cvtX(const float* __restrict__ x, unsigned short* __restrict__ xb,
                                              unsigned char* __restrict__ xq, int N, int Npad) {
    int i = blockIdx.x * THREADS + threadIdx.x;   // one 8-elem unit
    if (i >= Npad * 32) return;
    int row = i >> 5;
    unsigned short o[8];
    int q0 = 0, q1 = 0;
    if (row < N) {
        float4 v0 = reinterpret_cast<const float4*>(x)[2 * (size_t)i];
        float4 v1 = reinterpret_cast<const float4*>(x)[2 * (size_t)i + 1];
        o[0] = f2b(v0.x); o[1] = f2b(v0.y); o[2] = f2b(v0.z); o[3] = f2b(v0.w);
        o[4] = f2b(v1.x); o[5] = f2b(v1.y); o[6] = f2b(v1.z); o[7] = f2b(v1.w);
        q0 = __builtin_amdgcn_cvt_pk_fp8_f32(v0.x, v0.y, q0, false);
        q0 = __builtin_amdgcn_cvt_pk_fp8_f32(v0.z, v0.w, q0, true);
        q1 = __builtin_amdgcn_cvt_pk_fp8_f32(v1.x, v1.y, q1, false);
        q1 = __builtin_amdgcn_cvt_pk_fp8_f32(v1.z, v1.w, q1, true);
    } else {
        #pragma unroll
        for (int j = 0; j < 8; ++j) o[j] = 0;
    }
    reinterpret_cast<uint4*>(xb)[i] = *reinterpret_cast<uint4*>(o);
    reinterpret_cast<uint2*>(xq)[i] = make_uint2((unsigned)q0, (unsigned)q1);
}

// ---------------- build WbT[n][k] for layer1 (bf16) ----------------
__global__ __launch_bounds__(256) void k_cvtW(const float* __restrict__ W1l, const float* __restrict__ W1r,
                                              unsigned short* __restrict__ WbT) {
    int idx = blockIdx.x * THREADS + threadIdx.x;  // 256*512
    if (idx >= 256 * 512) return;
    int n = idx >> 9, k = idx & 511;
    float v = (k < 256) ? W1l[(size_t)k * 256 + n] : W1r[(size_t)(k - 256) * 256 + n];
    WbT[idx] = f2b(v);
}

// ---------------- build WbT2[n=80][k=256] for layer2 (bf16) ----------------
__global__ __launch_bounds__(256) void k_cvtW2(const float* __restrict__ W2l, const float* __restrict__ W2r,
                                               unsigned short* __restrict__ WbT2) {
    int idx = blockIdx.x * THREADS + threadIdx.x;  // 80*256
    if (idx >= 80 * 256) return;
    int n = idx >> 8, k = idx & 255;
    float v = (n < 40) ? W2l[(size_t)k * 40 + n] : W2r[(size_t)k * 40 + (n - 40)];
    WbT2[idx] = f2b(v);
}

// ---------------- layer-1 gather-aggregate (fp8): half-wave per node, 8 edges in flight ----------------
__global__ __launch_bounds__(256) void k_agg1(const int* __restrict__ rowptr, const int* __restrict__ csr_src,
                                              const float* __restrict__ dinv, const unsigned char* __restrict__ xq,
                                              unsigned short* __restrict__ aggb, int N, int Npad) {
    int gid = blockIdx.x * THREADS + threadIdx.x;
    int node = gid >> 5, lane = gid & 31;
    if (node >= N) {
        if (node < Npad)
            reinterpret_cast<uint4*>(aggb + (size_t)node * 256 + lane * 8)[0] = make_uint4(0, 0, 0, 0);
        return;
    }
    const int e0 = rowptr[node], e1 = rowptr[node + 1];
    const unsigned char* xl = xq + (size_t)lane * 8;
    float acc[8] = {};
    for (int eb = e0; eb < e1; eb += 32) {
        int n = min(32, e1 - eb);
        int sidx = (eb + lane < e1) ? csr_src[eb + lane] : 0;
        int j = 0;
        for (; j + 7 < n; j += 8) {
            uint2 vv[8];
            #pragma unroll
            for (int q = 0; q < 8; ++q) {
                int s = __shfl(sidx, j + q, 32);
                vv[q] = *reinterpret_cast<const uint2*>(xl + (size_t)s * 256);
            }
            #pragma unroll
            for (int q = 0; q < 8; ++q) {
                f32x2 p0 = __builtin_amdgcn_cvt_pk_f32_fp8((int)vv[q].x, false);
                f32x2 p1 = __builtin_amdgcn_cvt_pk_f32_fp8((int)vv[q].x, true);
                f32x2 p2 = __builtin_amdgcn_cvt_pk_f32_fp8((int)vv[q].y, false);
                f32x2 p3 = __builtin_amdgcn_cvt_pk_f32_fp8((int)vv[q].y, true);
                acc[0] += p0.x; acc[1] += p0.y;
                acc[2] += p1.x; acc[3] += p1.y;
                acc[4] += p2.x; acc[5] += p2.y;
                acc[6] += p3.x; acc[7] += p3.y;
            }
        }
        for (; j < n; ++j) {
            int s = __shfl(sidx, j, 32);
            uint2 v = *reinterpret_cast<const uint2*>(xl + (size_t)s * 256);
            f32x2 p0 = __builtin_amdgcn_cvt_pk_f32_fp8((int)v.x, false);
            f32x2 p1 = __builtin_amdgcn_cvt_pk_f32_fp8((int)v.x, true);
            f32x2 p2 = __builtin_amdgcn_cvt_pk_f32_fp8((int)v.y, false);
            f32x2 p3 = __builtin_amdgcn_cvt_pk_f32_fp8((int)v.y, true);
            acc[0] += p0.x; acc[1] += p0.y;
            acc[2] += p1.x; acc[3] += p1.y;
            acc[4] += p2.x; acc[5] += p2.y;
            acc[6] += p3.x; acc[7] += p3.y;
        }
    }
    const float ds = dinv[node];
    unsigned short o[8];
    #pragma unroll
    for (int j = 0; j < 8; ++j) o[j] = f2b(acc[j] * ds);
    *reinterpret_cast<uint4*>(aggb + (size_t)node * 256 + lane * 8) = *reinterpret_cast<uint4*>(o);
}

// ---------------- GEMM1 (bf16 MFMA, 512 thr, 128x256 tile): h = relu([agg|x] @ [W1l;W1r] + b1) ----------------
__global__ __launch_bounds__(512) void k_gemm1(
    const unsigned short* __restrict__ aggb, const unsigned short* __restrict__ xb,
    const unsigned short* __restrict__ WbT, const float* __restrict__ b1,
    unsigned short* __restrict__ hb, int M)
{
    __shared__ unsigned short As[128 * 64];   // 128 rows (M) x 64 k
    __shared__ unsigned short Bs[256 * 64];   // 256 rows (N) x 64 k

    const int tid  = threadIdx.x;
    const int lane = tid & 63;
    const int wave = tid >> 6;                // 0..7
    const int row0 = blockIdx.x * 128;
    const int wm0  = (wave >> 2) * 64;        // 0 or 64
    const int wn0  = (wave & 3) * 64;         // 0,64,128,192

    const int ldr = lane >> 3;                       // row within 8-row chunk
    const int lsw = ((lane & 7) ^ ldr) * 8;          // swizzled global 8-elem slot

    f32x4 acc[4][4];
    #pragma unroll
    for (int m = 0; m < 4; ++m)
        #pragma unroll
        for (int n = 0; n < 4; ++n)
            acc[m][n] = (f32x4){0.f, 0.f, 0.f, 0.f};

    for (int kt = 0; kt < 8; ++kt) {
        const unsigned short* Abase = (kt < 4) ? aggb : xb;
        const int kcol = (kt & 3) * 64;
        __syncthreads();
        #pragma unroll
        for (int i = 0; i < 2; ++i) {
            const int c = wave * 2 + i;              // A chunk 0..15
            const unsigned short* ga = Abase + (size_t)(row0 + c * 8 + ldr) * 256 + kcol + lsw;
            gload_lds16(ga, &As[c * 512]);
        }
        #pragma unroll
        for (int i = 0; i < 4; ++i) {
            const int c = wave * 4 + i;              // B chunk 0..31
            const unsigned short* gb = WbT + (size_t)(c * 8 + ldr) * 512 + kt * 64 + lsw;
            gload_lds16(gb, &Bs[c * 512]);
        }
        __syncthreads();
        #pragma unroll
        for (int kk = 0; kk < 2; ++kk) {
            bf16x8 af[4], bf[4];
            #pragma unroll
            for (int m = 0; m < 4; ++m) {
                const int r = wm0 + m * 16 + (lane & 15);
                const int s = (kk * 4 + (lane >> 4)) ^ (r & 7);
                af[m] = *reinterpret_cast<const bf16x8*>(&As[r * 64 + s * 8]);
            }
            #pragma unroll
            for (int n = 0; n < 4; ++n) {
                const int r = wn0 + n * 16 + (lane & 15);
                const int s = (kk * 4 + (lane >> 4)) ^ (r & 7);
                bf[n] = *reinterpret_cast<const bf16x8*>(&Bs[r * 64 + s * 8]);
            }
            #pragma unroll
            for (int m = 0; m < 4; ++m)
                #pragma unroll
                for (int n = 0; n < 4; ++n)
                    acc[m][n] = __builtin_amdgcn_mfma_f32_16x16x32_bf16(af[m], bf[n], acc[m][n], 0, 0, 0);
        }
    }

    const int crow = (lane >> 4) * 4;
    const int ccol = lane & 15;
    #pragma unroll
    for (int n = 0; n < 4; ++n) {
        const int col = wn0 + n * 16 + ccol;
        const float bias = b1[col];
        #pragma unroll
        for (int m = 0; m < 4; ++m) {
            const int rbase = row0 + wm0 + m * 16 + crow;
            #pragma unroll
            for (int r = 0; r < 4; ++r) {
                const int row = rbase + r;
                if (row < M) {
                    float v = fmaxf(acc[m][n][r] + bias, 0.f);
                    hb[(size_t)row * 256 + col] = f2b(v);
                }
            }
        }
    }
}

// ---------------- GEMM2 (bf16 MFMA): [Tq|Up] = h @ [W2l|W2r]; t in fp8, Up includes +b2 ----------------
__global__ __launch_bounds__(256) void k_gemm2(
    const unsigned short* __restrict__ hb, const unsigned short* __restrict__ WbT2,
    const float* __restrict__ b2,
    unsigned char* __restrict__ Tq, float* __restrict__ Up, int M)
{
    __shared__ unsigned short As[128 * 64];
    __shared__ unsigned short Bs2[80 * 264];   // padded stride 264 -> conflict-free frag reads

    const int tid  = threadIdx.x;
    const int lane = tid & 63;
    const int wave = tid >> 6;
    const int row0 = blockIdx.x * 128;

    const int ldr = lane >> 3;
    const int lsw = ((lane & 7) ^ ldr) * 8;

    // load B [80][256] into padded LDS once
    for (int idx = tid; idx < 80 * 32; idx += 256) {
        int row = idx >> 5, un = idx & 31;
        uint4 d = *reinterpret_cast<const uint4*>(WbT2 + (size_t)row * 256 + un * 8);
        *reinterpret_cast<uint4*>(&Bs2[row * 264 + un * 8]) = d;
    }

    f32x4 acc[2][5];
    #pragma unroll
    for (int m = 0; m < 2; ++m)
        #pragma unroll
        for (int n = 0; n < 5; ++n)
            acc[m][n] = (f32x4){0.f, 0.f, 0.f, 0.f};

    for (int kt = 0; kt < 4; ++kt) {
        __syncthreads();
        #pragma unroll
        for (int i = 0; i < 4; ++i) {
            const int c = wave * 4 + i;
            const unsigned short* ga = hb + (size_t)(row0 + c * 8 + ldr) * 256 + kt * 64 + lsw;
            gload_lds16(ga, &As[c * 512]);
        }
        __syncthreads();
        #pragma unroll
        for (int kk = 0; kk < 2; ++kk) {
            bf16x8 af[2], bf[5];
            #pragma unroll
            for (int m = 0; m < 2; ++m) {
                const int r = wave * 32 + m * 16 + (lane & 15);
                const int s = (kk * 4 + (lane >> 4)) ^ (r & 7);
                af[m] = *reinterpret_cast<const bf16x8*>(&As[(r & 127) * 64 + s * 8]);
            }
            #pragma unroll
            for (int n = 0; n < 5; ++n) {
                const int r = n * 16 + (lane & 15);
                bf[n] = *reinterpret_cast<const bf16x8*>(&Bs2[r * 264 + kt * 64 + kk * 32 + (lane >> 4) * 8]);
            }
            #pragma unroll
            for (int m = 0; m < 2; ++m)
                #pragma unroll
                for (int n = 0; n < 5; ++n)
                    acc[m][n] = __builtin_amdgcn_mfma_f32_16x16x32_bf16(af[m], bf[n], acc[m][n], 0, 0, 0);
        }
    }

    const int crow = (lane >> 4) * 4;
    const int ccol = lane & 15;
    #pragma unroll
    for (int n = 0; n < 5; ++n) {
        const int col = n * 16 + ccol;        // 0..79
        #pragma unroll
        for (int m = 0; m < 2; ++m) {
            const int rbase = row0 + wave * 32 + m * 16 + crow;
            #pragma unroll
            for (int r = 0; r < 4; ++r) {
                const int row = rbase + r;
                if (row < M) {
                    float v = acc[m][n][r];
                    if (col < 40) {
                        int q = __builtin_amdgcn_cvt_pk_fp8_f32(v, v, 0, false);
                        Tq[(size_t)row * 40 + col] = (unsigned char)(q & 0xff);
                    } else {
                        Up[(size_t)row * 40 + (col - 40)] = v + b2[col - 40];
                    }
                }
            }
        }
    }
}

// ---------------- fused layer-2 gather (fp8 Tq) + log_softmax: wave per node, 6 edges per VMEM ----------------
__global__ __launch_bounds__(256) void k_final(const int* __restrict__ rowptr, const int* __restrict__ csr_src,
                                               const float* __restrict__ dinv, const unsigned char* __restrict__ Tq,
                                               const float* __restrict__ Up, float* __restrict__ out, int N) {
    int gid = blockIdx.x * THREADS + threadIdx.x;
    int node = gid >> 6, lane = gid & 63;
    if (node >= N) return;
    const int e0 = rowptr[node], e1 = rowptr[node + 1];
    const int g = lane / 10;     // edge slot 0..5 (lanes 60-63 -> g=6, inactive)
    const int c = lane % 10;     // col part: uint = cols c*4 .. c*4+3 (fp8)
    float a0 = 0.f, a1 = 0.f, a2 = 0.f, a3 = 0.f;
    for (int eb = e0; eb < e1; eb += 64) {
        int sidx = (eb + lane < e1) ? csr_src[eb + lane] : 0;
        int nn = min(64, e1 - eb);
        for (int jb = 0; jb < nn; jb += 6) {
            int ei = jb + g;
            bool valid = (g < 6) && (ei < nn);
            int s = __shfl(sidx, ei & 63, 64);
            if (valid) {
                unsigned u = *reinterpret_cast<const unsigned*>(Tq + (size_t)s * 40 + c * 4);
                f32x2 lo = __builtin_amdgcn_cvt_pk_f32_fp8((int)u, false);
                f32x2 hi = __builtin_amdgcn_cvt_pk_f32_fp8((int)u, true);
                a0 += lo.x; a1 += lo.y;
                a2 += hi.x; a3 += hi.y;
            }
        }
    }
    // merge the 6 edge-groups: lanes (c + 10g) hold partials for col-part c.
    float t0 = a0, t1 = a1, t2 = a2, t3 = a3;
    #pragma unroll
    for (int gg = 1; gg < 6; ++gg) {
        t0 += __shfl(a0, c + 10 * gg, 64);
        t1 += __shfl(a1, c + 10 * gg, 64);
        t2 += __shfl(a2, c + 10 * gg, 64);
        t3 += __shfl(a3, c + 10 * gg, 64);
    }
    float v0 = -1e30f, v1 = -1e30f, v2 = -1e30f, v3 = -1e30f;
    if (lane < 10) {
        const float ds = dinv[node];
        float4 up = *reinterpret_cast<const float4*>(Up + (size_t)node * 40 + lane * 4);
        v0 = t0 * ds + up.x; v1 = t1 * ds + up.y;
        v2 = t2 * ds + up.z; v3 = t3 * ds + up.w;
    }
    float m = fmaxf(fmaxf(v0, v1), fmaxf(v2, v3));
    #pragma unroll
    for (int o = 8; o > 0; o >>= 1) m = fmaxf(m, __shfl_xor(m, o, 16));
    float e = 0.f;
    if (lane < 10) e = expf(v0 - m) + expf(v1 - m) + expf(v2 - m) + expf(v3 - m);
    float ssum = e;
    #pragma unroll
    for (int o = 8; o > 0; o >>= 1) ssum += __shfl_xor(ssum, o, 16);
    float ls = logf(ssum);
    if (lane < 10) {
        float4 o4;
        o4.x = v0 - m - ls; o4.y = v1 - m - ls;
        o4.z = v2 - m - ls; o4.w = v3 - m - ls;
        *reinterpret_cast<float4*>(out + (size_t)node * 40 + lane * 4) = o4;
    }
}

extern "C" void kernel_launch(void* const* d_in, const int* in_sizes, int n_in,
                              void* d_out, int out_size, void* d_ws, size_t ws_size,
                              hipStream_t stream) {
    const float* x   = (const float*)d_in[0];
    const int*   ei  = (const int*)d_in[1];
    const float* W1l = (const float*)d_in[2];
    const float* W1r = (const float*)d_in[3];
    const float* b1  = (const float*)d_in[4];
    const float* W2l = (const float*)d_in[5];
    const float* W2r = (const float*)d_in[6];
    const float* b2  = (const float*)d_in[7];
    float* out = (float*)d_out;

    const int N = in_sizes[0] / 256;
    const int E = in_sizes[1] / 2;
    const int Npad = ((N + 127) / 128) * 128;
    const int nbk = (N + 255) / 256;
    const int* src = ei;
    const int* dst = ei + E;

    char* ws = (char*)d_ws;
    size_t off = 0;
    int*   gcnt    = (int*)(ws + off); off += (size_t)NB_MAX * 4;
    int*   bptr    = (int*)(ws + off); off += (size_t)(NB_MAX + 1) * 4;
    int*   gcur    = (int*)(ws + off); off += (size_t)NB_MAX * 4;
    int*   rowptr  = (int*)(ws + off); off += (size_t)(N + 1) * 4;
    float* dinv    = (float*)(ws + off); off += (size_t)N * 4;
    off = (off + 255) & ~(size_t)255;
    unsigned* pairs = (unsigned*)(ws + off); off += (size_t)E * 4;
    int*   csr_src = (int*)(ws + off); off += (size_t)E * 4;
    off = (off + 255) & ~(size_t)255;
    unsigned short* xb   = (unsigned short*)(ws + off); off += (size_t)Npad * 256 * 2;
    unsigned char*  xq   = (unsigned char*)(ws + off);  off += (size_t)Npad * 256;
    unsigned short* aggb = (unsigned short*)(ws + off); off += (size_t)Npad * 256 * 2;
    unsigned short* hb   = (unsigned short*)(ws + off); off += (size_t)Npad * 256 * 2;
    unsigned short* WbT  = (unsigned short*)(ws + off); off += (size_t)256 * 512 * 2;
    unsigned short* WbT2 = (unsigned short*)(ws + off); off += (size_t)80 * 256 * 2;
    off = (off + 255) & ~(size_t)255;
    unsigned char* Tq    = (unsigned char*)(ws + off);  off += (size_t)Npad * 40;
    off = (off + 255) & ~(size_t)255;
    float*          Up   = (float*)(ws + off);          off += (size_t)Npad * 40 * 4;

    hipMemsetAsync(gcnt, 0, (size_t)NB_MAX * 4, stream);

    const int nsb = (E + 8191) / 8192;
    k_hist<<<nsb, THREADS, 0, stream>>>(dst, E, nbk, gcnt);
    k_scanb<<<1, 512, 0, stream>>>(gcnt, bptr, gcur, nbk, E);
    k_bucket_scatter<<<nsb, THREADS, 0, stream>>>(src, dst, gcur, pairs, E, nbk);
    k_bucket_csr<<<nbk, THREADS, 0, stream>>>(bptr, pairs, rowptr, dinv, csr_src, N, nbk, E);

    k_cvtX<<<(Npad * 32 + THREADS - 1) / THREADS, THREADS, 0, stream>>>(x, xb, xq, N, Npad);
    k_cvtW<<<(256 * 512 + THREADS - 1) / THREADS, THREADS, 0, stream>>>(W1l, W1r, WbT);
    k_cvtW2<<<(80 * 256 + THREADS - 1) / THREADS, THREADS, 0, stream>>>(W2l, W2r, WbT2);

    k_agg1<<<(Npad * 32 + THREADS - 1) / THREADS, THREADS, 0, stream>>>(rowptr, csr_src, dinv, xq, aggb, N, Npad);

    k_gemm1<<<Npad / 128, 512, 0, stream>>>(aggb, xb, WbT, b1, hb, N);

    k_gemm2<<<Npad / 128, THREADS, 0, stream>>>(hb, WbT2, b2, Tq, Up, N);

    k_final<<<((size_t)N * 64 + THREADS - 1) / THREADS, THREADS, 0, stream>>>(rowptr, csr_src, dinv, Tq, Up, out, N);
}